// Round 1
// baseline (545.887 us; speedup 1.0000x reference)
//
#include <hip/hip_runtime.h>
#include <hip/hip_bf16.h>
#include <math.h>

// GCN link predictor, fp32 throughout.
// Pipeline:
//   deg/dinv (atomic hist) -> CSR (counting sort) ->
//   h0 = x@W1+b1            [N,128]   (GEMM1, K=512)
//   agg1 = A@h0             [N,128]   (CSR gather-aggregate)
//   h1 = relu(agg1@Wc+bc)   [N,256]   (GEMM2)
//   h2 = h1@Wm              [N,128]   (GEMM3)
//   z  = A@h2 + bm          [N,128]   (aggregate + bias)
//   p = z@Wl[:128], q = z@Wl[128:]    (wave-per-node dot)
//   out[e] = sigmoid(p[src]+q[dst]+bl)

// ---------------- small utility kernels ----------------

__global__ __launch_bounds__(256) void init_kernel(float* deg, int* cnt, int n) {
    int i = blockIdx.x * 256 + threadIdx.x;
    if (i < n) { deg[i] = 1.0f; cnt[i] = 0; }   // self-loop weight 1
}

__global__ __launch_bounds__(256) void hist_kernel(const int* __restrict__ dst,
                                                   const float* __restrict__ w,
                                                   float* deg, int* cnt, int e) {
    int i = blockIdx.x * 256 + threadIdx.x;
    if (i < e) {
        int d = dst[i];
        atomicAdd(&deg[d], w[i]);
        atomicAdd(&cnt[d], 1);
    }
}

__global__ __launch_bounds__(256) void dinv_kernel(const float* __restrict__ deg,
                                                   float* __restrict__ dinv, int n) {
    int i = blockIdx.x * 256 + threadIdx.x;
    if (i < n) {
        float d = deg[i];
        dinv[i] = (d > 0.0f) ? (1.0f / sqrtf(d)) : 0.0f;   // d>=1 always, guard anyway
    }
}

__global__ __launch_bounds__(1024) void scan_partial(const int* __restrict__ cnt,
                                                     int* __restrict__ offs,
                                                     int* __restrict__ bsum, int n) {
    __shared__ int s[1024];
    int t = threadIdx.x;
    int i = blockIdx.x * 1024 + t;
    int v = (i < n) ? cnt[i] : 0;
    s[t] = v;
    __syncthreads();
    for (int off = 1; off < 1024; off <<= 1) {
        int add = (t >= off) ? s[t - off] : 0;
        __syncthreads();
        s[t] += add;
        __syncthreads();
    }
    if (i < n) offs[i] = s[t] - v;          // exclusive within block
    if (t == 1023) bsum[blockIdx.x] = s[t]; // block total
}

__global__ void scan_bsum(int* bsum, int* offs, int nblk, int n) {
    if (blockIdx.x == 0 && threadIdx.x == 0) {
        int running = 0;
        for (int b = 0; b < nblk; ++b) { int t = bsum[b]; bsum[b] = running; running += t; }
        offs[n] = running;  // == E
    }
}

__global__ __launch_bounds__(256) void scan_add(int* __restrict__ offs,
                                                const int* __restrict__ bsum,
                                                int* __restrict__ cursor, int n) {
    int i = blockIdx.x * 256 + threadIdx.x;
    if (i < n) {
        int v = offs[i] + bsum[i >> 10];
        offs[i] = v;
        cursor[i] = v;
    }
}

__global__ __launch_bounds__(256) void scatter_kernel(const int* __restrict__ src,
                                                      const int* __restrict__ dst,
                                                      const float* __restrict__ w,
                                                      const float* __restrict__ dinv,
                                                      int* cursor,
                                                      int* __restrict__ es,
                                                      float* __restrict__ en, int e) {
    int i = blockIdx.x * 256 + threadIdx.x;
    if (i < e) {
        int s = src[i], d = dst[i];
        float nrm = dinv[s] * w[i] * dinv[d];
        int pos = atomicAdd(&cursor[d], 1);
        es[pos] = s;
        en[pos] = nrm;
    }
}

// ---------------- fp32 tiled GEMM: C[M,N] = A[M,K] @ B[K,N] (+bias)(+relu) ----------------
// BM=64, BN=128, BK=16; 256 threads, each computes 8x4.
template<bool BIAS, bool RELU>
__global__ __launch_bounds__(256) void gemm_f32(const float* __restrict__ A,
                                                const float* __restrict__ B,
                                                const float* __restrict__ bias,
                                                float* __restrict__ C,
                                                int M, int K, int Nn) {
    constexpr int BM = 64, BN = 128, BK = 16;
    __shared__ float As[BK][BM];
    __shared__ float Bs[BK][BN];
    int t = threadIdx.x;
    int bm = blockIdx.x * BM;
    int bn = blockIdx.y * BN;
    int m0 = (t >> 5) * 8;   // 0..56
    int n0 = (t & 31) * 4;   // 0..124

    float acc[8][4] = {};

    for (int k0 = 0; k0 < K; k0 += BK) {
        // stage A tile (transposed into LDS): thread -> row=t>>2, kk=(t&3)*4
        {
            int row = t >> 2;
            int kk  = (t & 3) * 4;
            int gm  = bm + row;
            float4 v = make_float4(0.f, 0.f, 0.f, 0.f);
            if (gm < M) v = *(const float4*)(A + (size_t)gm * K + k0 + kk);
            As[kk + 0][row] = v.x;
            As[kk + 1][row] = v.y;
            As[kk + 2][row] = v.z;
            As[kk + 3][row] = v.w;
        }
        // stage B tile (row-major)
        {
#pragma unroll
            for (int part = 0; part < 2; ++part) {
                int idx = part * 1024 + t * 4;
                int r = idx >> 7, c = idx & 127;
                float4 v = *(const float4*)(B + (size_t)(k0 + r) * Nn + bn + c);
                *(float4*)&Bs[r][c] = v;
            }
        }
        __syncthreads();
#pragma unroll
        for (int kk = 0; kk < BK; ++kk) {
            float4 a0 = *(const float4*)&As[kk][m0];
            float4 a1 = *(const float4*)&As[kk][m0 + 4];
            float4 bv = *(const float4*)&Bs[kk][n0];
            float am[8] = {a0.x, a0.y, a0.z, a0.w, a1.x, a1.y, a1.z, a1.w};
            float bb[4] = {bv.x, bv.y, bv.z, bv.w};
#pragma unroll
            for (int ii = 0; ii < 8; ++ii)
#pragma unroll
                for (int jj = 0; jj < 4; ++jj)
                    acc[ii][jj] += am[ii] * bb[jj];
        }
        __syncthreads();
    }

    float bfrag[4] = {0.f, 0.f, 0.f, 0.f};
    if (BIAS) {
        float4 bb = *(const float4*)(bias + bn + n0);
        bfrag[0] = bb.x; bfrag[1] = bb.y; bfrag[2] = bb.z; bfrag[3] = bb.w;
    }
#pragma unroll
    for (int ii = 0; ii < 8; ++ii) {
        int gm = bm + m0 + ii;
        if (gm < M) {
            float4 o;
            o.x = acc[ii][0] + bfrag[0];
            o.y = acc[ii][1] + bfrag[1];
            o.z = acc[ii][2] + bfrag[2];
            o.w = acc[ii][3] + bfrag[3];
            if (RELU) {
                o.x = fmaxf(o.x, 0.f); o.y = fmaxf(o.y, 0.f);
                o.z = fmaxf(o.z, 0.f); o.w = fmaxf(o.w, 0.f);
            }
            *(float4*)(C + (size_t)gm * Nn + bn + n0) = o;
        }
    }
}

// ---------------- CSR aggregation: out[i] = dinv[i]^2*h[i] + sum_e norm*h[es[e]] (+bias) ----------------
// H == 128 columns; one wave (64 lanes) per node, float2 per lane.
template<bool ADD_BIAS>
__global__ __launch_bounds__(256) void aggregate128(const float* __restrict__ h,
                                                    const int* __restrict__ offs,
                                                    const int* __restrict__ es,
                                                    const float* __restrict__ en,
                                                    const float* __restrict__ dinv,
                                                    const float* __restrict__ bias,
                                                    float* __restrict__ out, int n) {
    int wave = (int)((blockIdx.x * (size_t)blockDim.x + threadIdx.x) >> 6);
    int lane = threadIdx.x & 63;
    if (wave >= n) return;
    int i = wave;
    float di = dinv[i];
    float sw = di * di;
    float2 hv = ((const float2*)(h + (size_t)i * 128))[lane];
    float ax = sw * hv.x, ay = sw * hv.y;
    int beg = offs[i], end = offs[i + 1];
    for (int e = beg; e < end; ++e) {
        int s   = es[e];
        float wN = en[e];
        float2 v = ((const float2*)(h + (size_t)s * 128))[lane];
        ax += wN * v.x;
        ay += wN * v.y;
    }
    if (ADD_BIAS) {
        ax += bias[lane * 2];
        ay += bias[lane * 2 + 1];
    }
    float2 o; o.x = ax; o.y = ay;
    ((float2*)(out + (size_t)i * 128))[lane] = o;
}

// ---------------- p/q: per-node dots with W_lin halves ----------------
__global__ __launch_bounds__(256) void pq_kernel(const float* __restrict__ z,
                                                 const float* __restrict__ wl,
                                                 float* __restrict__ p,
                                                 float* __restrict__ q, int n) {
    int wave = (int)((blockIdx.x * (size_t)blockDim.x + threadIdx.x) >> 6);
    int lane = threadIdx.x & 63;
    if (wave >= n) return;
    float2 zv = ((const float2*)(z + (size_t)wave * 128))[lane];
    float2 wp = ((const float2*)wl)[lane];
    float2 wq = ((const float2*)(wl + 128))[lane];
    float pp = zv.x * wp.x + zv.y * wp.y;
    float qq = zv.x * wq.x + zv.y * wq.y;
#pragma unroll
    for (int off = 32; off > 0; off >>= 1) {
        pp += __shfl_down(pp, off);
        qq += __shfl_down(qq, off);
    }
    if (lane == 0) { p[wave] = pp; q[wave] = qq; }
}

__global__ __launch_bounds__(256) void edge_out_kernel(const int* __restrict__ src,
                                                       const int* __restrict__ dst,
                                                       const float* __restrict__ p,
                                                       const float* __restrict__ q,
                                                       const float* __restrict__ bl,
                                                       float* __restrict__ out, int e) {
    int i = blockIdx.x * 256 + threadIdx.x;
    if (i < e) {
        float t = p[src[i]] + q[dst[i]] + bl[0];
        out[i] = 1.0f / (1.0f + expf(-t));
    }
}

// ---------------- launch ----------------

extern "C" void kernel_launch(void* const* d_in, const int* in_sizes, int n_in,
                              void* d_out, int out_size, void* d_ws, size_t ws_size,
                              hipStream_t stream) {
    const int*   edge_index = (const int*)d_in[0];
    const float* x   = (const float*)d_in[1];
    const float* w   = (const float*)d_in[2];
    const float* W1  = (const float*)d_in[3];
    const float* b1  = (const float*)d_in[4];
    const float* Wc  = (const float*)d_in[5];
    const float* bc  = (const float*)d_in[6];
    const float* Wm  = (const float*)d_in[7];
    const float* bm  = (const float*)d_in[8];
    const float* Wl  = (const float*)d_in[9];
    const float* bl  = (const float*)d_in[10];
    float* out = (float*)d_out;

    const int E  = in_sizes[2];            // 800000
    const int H  = in_sizes[4];            // 128
    const int F  = in_sizes[3] / H;        // 512
    const int N  = in_sizes[1] / F;        // 50000
    const int H2 = 2 * H;                  // 256

    const int* src = edge_index;
    const int* dst = edge_index + E;

    // workspace carve-up (~110 MB total)
    char* ws = (char*)d_ws;
    size_t off = 0;
    auto alloc = [&](size_t bytes) -> void* {
        off = (off + 255) & ~(size_t)255;
        void* r = ws + off;
        off += bytes;
        return r;
    };
    float* deg    = (float*)alloc((size_t)N * 4);
    float* dinv   = (float*)alloc((size_t)N * 4);
    int*   cnt    = (int*)  alloc((size_t)N * 4);
    int*   offs   = (int*)  alloc((size_t)(N + 1) * 4);
    int*   cursor = (int*)  alloc((size_t)N * 4);
    int*   bsum   = (int*)  alloc(256 * 4);
    int*   es     = (int*)  alloc((size_t)E * 4);
    float* en     = (float*)alloc((size_t)E * 4);
    float* hA     = (float*)alloc((size_t)N * H * 4);   // h0, later h2
    float* hB     = (float*)alloc((size_t)N * H * 4);   // agg1, later z
    float* h1     = (float*)alloc((size_t)N * H2 * 4);  // conv1 output
    float* p      = (float*)alloc((size_t)N * 4);
    float* q      = (float*)alloc((size_t)N * 4);
    (void)ws_size; (void)n_in; (void)out_size;

    int nbN = (N + 255) / 256;
    int nbE = (E + 255) / 256;
    int nblk = (N + 1023) / 1024;
    int nbW = (int)(((size_t)N * 64 + 255) / 256);  // wave-per-node launches

    // degree + CSR build
    init_kernel<<<nbN, 256, 0, stream>>>(deg, cnt, N);
    hist_kernel<<<nbE, 256, 0, stream>>>(dst, w, deg, cnt, E);
    dinv_kernel<<<nbN, 256, 0, stream>>>(deg, dinv, N);
    scan_partial<<<nblk, 1024, 0, stream>>>(cnt, offs, bsum, N);
    scan_bsum<<<1, 1, 0, stream>>>(bsum, offs, nblk, N);
    scan_add<<<nbN, 256, 0, stream>>>(offs, bsum, cursor, N);
    scatter_kernel<<<nbE, 256, 0, stream>>>(src, dst, w, dinv, cursor, es, en, E);

    // h0 = x @ W1 + b1      [N,128]
    gemm_f32<true, false><<<dim3((N + 63) / 64, H / 128), 256, 0, stream>>>(x, W1, b1, hA, N, F, H);
    // agg1 = A @ h0         [N,128]
    aggregate128<false><<<nbW, 256, 0, stream>>>(hA, offs, es, en, dinv, nullptr, hB, N);
    // h1 = relu(agg1 @ Wc + bc)   [N,256]
    gemm_f32<true, true><<<dim3((N + 63) / 64, H2 / 128), 256, 0, stream>>>(hB, Wc, bc, h1, N, H, H2);
    // h2 = h1 @ Wm          [N,128]
    gemm_f32<false, false><<<dim3((N + 63) / 64, H / 128), 256, 0, stream>>>(h1, Wm, nullptr, hA, N, H2, H);
    // z = A @ h2 + bm       [N,128]
    aggregate128<true><<<nbW, 256, 0, stream>>>(hA, offs, es, en, dinv, bm, hB, N);
    // p,q
    pq_kernel<<<nbW, 256, 0, stream>>>(hB, Wl, p, q, N);
    // out
    edge_out_kernel<<<nbE, 256, 0, stream>>>(src, dst, p, q, bl, out, E);
}

// Round 2
// 323.043 us; speedup vs baseline: 1.6898x; 1.6898x over previous
//
#include <hip/hip_runtime.h>
#include <hip/hip_bf16.h>
#include <math.h>

// GCN link predictor, bf16 MFMA pipeline.
//   CSR build (hist/scan/scatter)
//   h0_bf = bf16(x @ W1 + b1)            [N,128]  MFMA GEMM, fused f32->bf16
//   agg1_bf = bf16(A_norm @ h0_bf)       [N,128]  wave-per-node aggregate
//   pe,qe = relu(agg1 @ Wc + bc) @ [wmp,wmq]      MFMA GEMM fused epilogue
//           (wmp = Wm @ Wl[:128], wmq = Wm @ Wl[128:], h1 never materialized)
//   p = A_norm @ pe + bm.wp ; q = A_norm @ qe + bm.wq   (scalar aggregate)
//   out[e] = sigmoid(p[src] + q[dst] + bl)

typedef __attribute__((ext_vector_type(8))) short bf16x8;
typedef __attribute__((ext_vector_type(4))) float f32x4;

static __device__ __forceinline__ ushort f2b(float f) {
    __hip_bfloat16 h = __float2bfloat16(f);
    return *(ushort*)&h;
}
static __device__ __forceinline__ float b2f(ushort u) {
    unsigned int v = ((unsigned int)u) << 16;
    return *(float*)&v;
}

// ---------------- CSR build ----------------

__global__ __launch_bounds__(256) void init_kernel(float* deg, int* cnt, int n) {
    int i = blockIdx.x * 256 + threadIdx.x;
    if (i < n) { deg[i] = 1.0f; cnt[i] = 0; }   // self-loop weight 1
}

__global__ __launch_bounds__(256) void hist_kernel(const int* __restrict__ dst,
                                                   const float* __restrict__ w,
                                                   float* deg, int* cnt, int e) {
    int i = blockIdx.x * 256 + threadIdx.x;
    if (i < e) {
        int d = dst[i];
        atomicAdd(&deg[d], w[i]);
        atomicAdd(&cnt[d], 1);
    }
}

__global__ __launch_bounds__(256) void dinv_kernel(const float* __restrict__ deg,
                                                   float* __restrict__ dinv, int n) {
    int i = blockIdx.x * 256 + threadIdx.x;
    if (i < n) {
        float d = deg[i];
        dinv[i] = (d > 0.0f) ? (1.0f / sqrtf(d)) : 0.0f;
    }
}

__global__ __launch_bounds__(1024) void scan_partial(const int* __restrict__ cnt,
                                                     int* __restrict__ offs,
                                                     int* __restrict__ bsum, int n) {
    __shared__ int s[1024];
    int t = threadIdx.x;
    int i = blockIdx.x * 1024 + t;
    int v = (i < n) ? cnt[i] : 0;
    s[t] = v;
    __syncthreads();
    for (int off = 1; off < 1024; off <<= 1) {
        int add = (t >= off) ? s[t - off] : 0;
        __syncthreads();
        s[t] += add;
        __syncthreads();
    }
    if (i < n) offs[i] = s[t] - v;
    if (t == 1023) bsum[blockIdx.x] = s[t];
}

__global__ void scan_bsum(int* bsum, int* offs, int nblk, int n) {
    if (blockIdx.x == 0 && threadIdx.x == 0) {
        int running = 0;
        for (int b = 0; b < nblk; ++b) { int t = bsum[b]; bsum[b] = running; running += t; }
        offs[n] = running;
    }
}

__global__ __launch_bounds__(256) void scan_add(int* __restrict__ offs,
                                                const int* __restrict__ bsum,
                                                int* __restrict__ cursor, int n) {
    int i = blockIdx.x * 256 + threadIdx.x;
    if (i < n) {
        int v = offs[i] + bsum[i >> 10];
        offs[i] = v;
        cursor[i] = v;
    }
}

__global__ __launch_bounds__(256) void scatter_kernel(const int* __restrict__ src,
                                                      const int* __restrict__ dst,
                                                      const float* __restrict__ w,
                                                      const float* __restrict__ dinv,
                                                      int* cursor,
                                                      int* __restrict__ es,
                                                      float* __restrict__ en, int e) {
    int i = blockIdx.x * 256 + threadIdx.x;
    if (i < e) {
        int s = src[i], d = dst[i];
        float nrm = dinv[s] * w[i] * dinv[d];
        int pos = atomicAdd(&cursor[d], 1);
        es[pos] = s;
        en[pos] = nrm;
    }
}

// ---------------- weight prep ----------------

// BT[n][k] = bf16(B[k][n])
__global__ __launch_bounds__(256) void tconv_kernel(const float* __restrict__ B,
                                                    ushort* __restrict__ BT, int K, int Nn) {
    int i = blockIdx.x * 256 + threadIdx.x;
    if (i < K * Nn) {
        int k = i / Nn, n = i % Nn;
        BT[(size_t)n * K + k] = f2b(B[i]);
    }
}

// wmp = Wm @ Wl[:128], wmq = Wm @ Wl[128:], bpq = {bm.wp, bm.wq}
__global__ __launch_bounds__(256) void fold_kernel(const float* __restrict__ Wm,
                                                   const float* __restrict__ Wl,
                                                   const float* __restrict__ bm,
                                                   float* __restrict__ wmp,
                                                   float* __restrict__ wmq,
                                                   float* __restrict__ bpq) {
    int j = threadIdx.x;
    float sp = 0.f, sq = 0.f;
    for (int k = 0; k < 128; ++k) {
        float v = Wm[(size_t)j * 128 + k];
        sp += v * Wl[k];
        sq += v * Wl[128 + k];
    }
    wmp[j] = sp; wmq[j] = sq;
    if (j == 0) { float s = 0.f; for (int k = 0; k < 128; ++k) s += bm[k] * Wl[k];       bpq[0] = s; }
    if (j == 1) { float s = 0.f; for (int k = 0; k < 128; ++k) s += bm[k] * Wl[128 + k]; bpq[1] = s; }
}

// ---------------- GEMM1: h0_bf = bf16(x @ W1 + b1), MFMA, fused f32->bf16 staging ----------------
// BM=128, BN=128, K=512, BK=64. 256 threads = 4 waves (2x2), wave tile 64x64.
__global__ __launch_bounds__(256) void gemm1_mfma(const float* __restrict__ A,
                                                  const ushort* __restrict__ BT,  // [128][512] bf16
                                                  const float* __restrict__ bias,
                                                  ushort* __restrict__ C, int M) {
    __shared__ ushort As[128 * 64];
    __shared__ ushort Bs[128 * 64];
    const int t = threadIdx.x;
    const int bm = blockIdx.x * 128;
    const int lane = t & 63;
    const int wid = t >> 6;
    const int wm = (wid >> 1) * 64, wn = (wid & 1) * 64;

    f32x4 acc[4][4] = {};

    const int arow = t >> 1, acb = (t & 1) * 32;   // A stage: 8 float4 per thread
    const int brow = t >> 1, bcb = (t & 1) * 32;   // B stage: 4 x 16B per thread

    for (int k0 = 0; k0 < 512; k0 += 64) {
        // stage A (fp32 -> bf16, swizzled)
        {
            const float* ap = A + (size_t)(bm + arow) * 512 + k0 + acb;
            const bool valid = (bm + arow) < M;
#pragma unroll
            for (int j = 0; j < 8; ++j) {
                float4 f = valid ? *(const float4*)(ap + j * 4) : make_float4(0.f, 0.f, 0.f, 0.f);
                ushort4 u;
                u.x = f2b(f.x); u.y = f2b(f.y); u.z = f2b(f.z); u.w = f2b(f.w);
                int byte = (arow * 128 + (acb + j * 4) * 2) ^ ((arow & 7) << 4);
                *(ushort4*)((char*)As + byte) = u;
            }
        }
        // stage B (bf16, swizzled)
        {
            const ushort* bp = BT + (size_t)brow * 512 + k0 + bcb;
#pragma unroll
            for (int j = 0; j < 4; ++j) {
                uint4 u = *(const uint4*)(bp + j * 8);
                int byte = (brow * 128 + (bcb + j * 8) * 2) ^ ((brow & 7) << 4);
                *(uint4*)((char*)Bs + byte) = u;
            }
        }
        __syncthreads();
#pragma unroll
        for (int ks = 0; ks < 2; ++ks) {
            bf16x8 af[4], bfr[4];
#pragma unroll
            for (int mi = 0; mi < 4; ++mi) {
                int row = wm + mi * 16 + (lane & 15);
                int byte = (row * 128 + ks * 64 + (lane >> 4) * 16) ^ ((row & 7) << 4);
                af[mi] = *(bf16x8*)((char*)As + byte);
            }
#pragma unroll
            for (int ni = 0; ni < 4; ++ni) {
                int row = wn + ni * 16 + (lane & 15);
                int byte = (row * 128 + ks * 64 + (lane >> 4) * 16) ^ ((row & 7) << 4);
                bfr[ni] = *(bf16x8*)((char*)Bs + byte);
            }
#pragma unroll
            for (int mi = 0; mi < 4; ++mi)
#pragma unroll
                for (int ni = 0; ni < 4; ++ni)
                    acc[mi][ni] = __builtin_amdgcn_mfma_f32_16x16x32_bf16(af[mi], bfr[ni], acc[mi][ni], 0, 0, 0);
        }
        __syncthreads();
    }
    // epilogue: + bias, -> bf16
#pragma unroll
    for (int ni = 0; ni < 4; ++ni) {
        int col = wn + ni * 16 + (lane & 15);
        float bv = bias[col];
#pragma unroll
        for (int mi = 0; mi < 4; ++mi)
#pragma unroll
            for (int r = 0; r < 4; ++r) {
                int row = bm + wm + mi * 16 + (lane >> 4) * 4 + r;
                if (row < M) C[(size_t)row * 128 + col] = f2b(acc[mi][ni][r] + bv);
            }
    }
}

// ---------------- aggregate (bf16 in/out): out[i] = dinv[i]^2*h[i] + sum norm*h[es] ----------------
__global__ __launch_bounds__(256) void aggregate_bf16(const ushort* __restrict__ h,
                                                      const int* __restrict__ offs,
                                                      const int* __restrict__ es,
                                                      const float* __restrict__ en,
                                                      const float* __restrict__ dinv,
                                                      ushort* __restrict__ out, int n) {
    int wave = (int)((blockIdx.x * (size_t)blockDim.x + threadIdx.x) >> 6);
    int lane = threadIdx.x & 63;
    if (wave >= n) return;
    float di = dinv[wave];
    float sw = di * di;
    unsigned int hv = *(const unsigned int*)(h + (size_t)wave * 128 + lane * 2);
    float ax = sw * b2f((ushort)(hv & 0xffff));
    float ay = sw * b2f((ushort)(hv >> 16));
    int beg = offs[wave], end = offs[wave + 1];
    for (int e = beg; e < end; ++e) {
        int s = es[e];
        float wN = en[e];
        unsigned int v = *(const unsigned int*)(h + (size_t)s * 128 + lane * 2);
        ax += wN * b2f((ushort)(v & 0xffff));
        ay += wN * b2f((ushort)(v >> 16));
    }
    unsigned int o = (unsigned int)f2b(ax) | ((unsigned int)f2b(ay) << 16);
    *(unsigned int*)(out + (size_t)wave * 128 + lane * 2) = o;
}

// ---------------- GEMM2 fused: pe,qe = relu(agg1@Wc + bc) @ [wmp,wmq] ----------------
// BM=128, BN=256 (full), K=128, BK=64. 512 threads = 8 waves (2M x 4N), wave tile 64x64.
__global__ __launch_bounds__(512) void gemm2_pq(const ushort* __restrict__ A,   // [M][128] bf16
                                                const ushort* __restrict__ BT,  // [256][128] bf16
                                                const float* __restrict__ bc,
                                                const float* __restrict__ wmp,
                                                const float* __restrict__ wmq,
                                                float* __restrict__ pe,
                                                float* __restrict__ qe, int M) {
    __shared__ ushort As[128 * 64];
    __shared__ ushort Bs[256 * 64];
    __shared__ float partp[4][128];
    __shared__ float partq[4][128];
    const int t = threadIdx.x;
    const int bm = blockIdx.x * 128;
    const int lane = t & 63;
    const int wid = t >> 6;
    const int wm = (wid >> 2) * 64, wn = (wid & 3) * 64;

    f32x4 acc[4][4] = {};

    for (int k0 = 0; k0 < 128; k0 += 64) {
        // stage A: 128x64 bf16, 2 x 16B per thread
        {
            int row = t >> 2, cb = (t & 3) * 16;
            const bool valid = (bm + row) < M;
            const ushort* ap = A + (size_t)(bm + row) * 128 + k0 + cb;
#pragma unroll
            for (int j = 0; j < 2; ++j) {
                uint4 u = valid ? *(const uint4*)(ap + j * 8) : make_uint4(0, 0, 0, 0);
                int byte = (row * 128 + (cb + j * 8) * 2) ^ ((row & 7) << 4);
                *(uint4*)((char*)As + byte) = u;
            }
        }
        // stage B: 256x64 bf16, 4 x 16B per thread
        {
            int row = t >> 1, cb = (t & 1) * 32;
            const ushort* bp = BT + (size_t)row * 128 + k0 + cb;
#pragma unroll
            for (int j = 0; j < 4; ++j) {
                uint4 u = *(const uint4*)(bp + j * 8);
                int byte = (row * 128 + (cb + j * 8) * 2) ^ ((row & 7) << 4);
                *(uint4*)((char*)Bs + byte) = u;
            }
        }
        __syncthreads();
#pragma unroll
        for (int ks = 0; ks < 2; ++ks) {
            bf16x8 af[4], bfr[4];
#pragma unroll
            for (int mi = 0; mi < 4; ++mi) {
                int row = wm + mi * 16 + (lane & 15);
                int byte = (row * 128 + ks * 64 + (lane >> 4) * 16) ^ ((row & 7) << 4);
                af[mi] = *(bf16x8*)((char*)As + byte);
            }
#pragma unroll
            for (int ni = 0; ni < 4; ++ni) {
                int row = wn + ni * 16 + (lane & 15);
                int byte = (row * 128 + ks * 64 + (lane >> 4) * 16) ^ ((row & 7) << 4);
                bfr[ni] = *(bf16x8*)((char*)Bs + byte);
            }
#pragma unroll
            for (int mi = 0; mi < 4; ++mi)
#pragma unroll
                for (int ni = 0; ni < 4; ++ni)
                    acc[mi][ni] = __builtin_amdgcn_mfma_f32_16x16x32_bf16(af[mi], bfr[ni], acc[mi][ni], 0, 0, 0);
        }
        __syncthreads();
    }

    // epilogue: bias + relu + dot with wmp/wmq, reduce over N
    float bcv[4], wpv[4], wqv[4];
#pragma unroll
    for (int ni = 0; ni < 4; ++ni) {
        int col = wn + ni * 16 + (lane & 15);
        bcv[ni] = bc[col];
        wpv[ni] = wmp[col];
        wqv[ni] = wmq[col];
    }
#pragma unroll
    for (int mi = 0; mi < 4; ++mi) {
#pragma unroll
        for (int r = 0; r < 4; ++r) {
            float sp = 0.f, sq = 0.f;
#pragma unroll
            for (int ni = 0; ni < 4; ++ni) {
                float h = fmaxf(acc[mi][ni][r] + bcv[ni], 0.f);
                sp += h * wpv[ni];
                sq += h * wqv[ni];
            }
#pragma unroll
            for (int off = 1; off < 16; off <<= 1) {
                sp += __shfl_xor(sp, off);
                sq += __shfl_xor(sq, off);
            }
            if ((lane & 15) == 0) {
                int row = wm + mi * 16 + (lane >> 4) * 4 + r;   // 0..127
                partp[wid & 3][row] = sp;
                partq[wid & 3][row] = sq;
            }
        }
    }
    __syncthreads();
    if (t < 128) {
        int row = t;
        if (bm + row < M)
            pe[bm + row] = partp[0][row] + partp[1][row] + partp[2][row] + partp[3][row];
    } else if (t < 256) {
        int row = t - 128;
        if (bm + row < M)
            qe[bm + row] = partq[0][row] + partq[1][row] + partq[2][row] + partq[3][row];
    }
}

// ---------------- scalar aggregation: p = A@pe + bp, q = A@qe + bq ----------------
__global__ __launch_bounds__(256) void agg_scalar(const float* __restrict__ pe,
                                                  const float* __restrict__ qe,
                                                  const int* __restrict__ offs,
                                                  const int* __restrict__ es,
                                                  const float* __restrict__ en,
                                                  const float* __restrict__ dinv,
                                                  const float* __restrict__ bpq,
                                                  float* __restrict__ p,
                                                  float* __restrict__ q, int n) {
    int i = blockIdx.x * 256 + threadIdx.x;
    if (i >= n) return;
    float di = dinv[i];
    float sw = di * di;
    float ap = sw * pe[i], aq = sw * qe[i];
    int beg = offs[i], end = offs[i + 1];
    for (int k = beg; k < end; ++k) {
        int s = es[k];
        float wN = en[k];
        ap += wN * pe[s];
        aq += wN * qe[s];
    }
    p[i] = ap + bpq[0];
    q[i] = aq + bpq[1];
}

__global__ __launch_bounds__(256) void edge_out_kernel(const int* __restrict__ src,
                                                       const int* __restrict__ dst,
                                                       const float* __restrict__ p,
                                                       const float* __restrict__ q,
                                                       const float* __restrict__ bl,
                                                       float* __restrict__ out, int e) {
    int i = blockIdx.x * 256 + threadIdx.x;
    if (i < e) {
        float t = p[src[i]] + q[dst[i]] + bl[0];
        out[i] = 1.0f / (1.0f + expf(-t));
    }
}

// ---------------- launch ----------------

extern "C" void kernel_launch(void* const* d_in, const int* in_sizes, int n_in,
                              void* d_out, int out_size, void* d_ws, size_t ws_size,
                              hipStream_t stream) {
    const int*   edge_index = (const int*)d_in[0];
    const float* x   = (const float*)d_in[1];
    const float* w   = (const float*)d_in[2];
    const float* W1  = (const float*)d_in[3];
    const float* b1  = (const float*)d_in[4];
    const float* Wc  = (const float*)d_in[5];
    const float* bc  = (const float*)d_in[6];
    const float* Wm  = (const float*)d_in[7];
    const float* bm  = (const float*)d_in[8];
    const float* Wl  = (const float*)d_in[9];
    const float* bl  = (const float*)d_in[10];
    float* out = (float*)d_out;

    const int E  = in_sizes[2];            // 800000
    const int H  = in_sizes[4];            // 128
    const int F  = in_sizes[3] / H;        // 512
    const int N  = in_sizes[1] / F;        // 50000
    const int H2 = 2 * H;                  // 256

    const int* src = edge_index;
    const int* dst = edge_index + E;

    char* ws = (char*)d_ws;
    size_t off = 0;
    auto alloc = [&](size_t bytes) -> void* {
        off = (off + 255) & ~(size_t)255;
        void* r = ws + off;
        off += bytes;
        return r;
    };
    float*  deg     = (float*) alloc((size_t)N * 4);
    float*  dinv    = (float*) alloc((size_t)N * 4);
    int*    cnt     = (int*)   alloc((size_t)N * 4);
    int*    offs    = (int*)   alloc((size_t)(N + 1) * 4);
    int*    cursor  = (int*)   alloc((size_t)N * 4);
    int*    bsum    = (int*)   alloc(256 * 4);
    int*    es      = (int*)   alloc((size_t)E * 4);
    float*  en      = (float*) alloc((size_t)E * 4);
    ushort* h0_bf   = (ushort*)alloc((size_t)N * H * 2);
    ushort* agg1_bf = (ushort*)alloc((size_t)N * H * 2);
    ushort* W1T     = (ushort*)alloc((size_t)H * F * 2);   // [128][512]
    ushort* WcT     = (ushort*)alloc((size_t)H2 * H * 2);  // [256][128]
    float*  wmp     = (float*) alloc(H2 * 4);
    float*  wmq     = (float*) alloc(H2 * 4);
    float*  bpq     = (float*) alloc(2 * 4);
    float*  pe      = (float*) alloc((size_t)N * 4);
    float*  qe      = (float*) alloc((size_t)N * 4);
    float*  p       = (float*) alloc((size_t)N * 4);
    float*  q       = (float*) alloc((size_t)N * 4);
    (void)ws_size; (void)n_in; (void)out_size;

    int nbN  = (N + 255) / 256;
    int nbE  = (E + 255) / 256;
    int nblk = (N + 1023) / 1024;
    int nbW  = (int)(((size_t)N * 64 + 255) / 256);
    int nbM  = (N + 127) / 128;

    // CSR build
    init_kernel<<<nbN, 256, 0, stream>>>(deg, cnt, N);
    hist_kernel<<<nbE, 256, 0, stream>>>(dst, w, deg, cnt, E);
    dinv_kernel<<<nbN, 256, 0, stream>>>(deg, dinv, N);
    scan_partial<<<nblk, 1024, 0, stream>>>(cnt, offs, bsum, N);
    scan_bsum<<<1, 1, 0, stream>>>(bsum, offs, nblk, N);
    scan_add<<<nbN, 256, 0, stream>>>(offs, bsum, cursor, N);
    scatter_kernel<<<nbE, 256, 0, stream>>>(src, dst, w, dinv, cursor, es, en, E);

    // weight prep (independent of CSR; cheap)
    tconv_kernel<<<(F * H + 255) / 256, 256, 0, stream>>>(W1, W1T, F, H);
    tconv_kernel<<<(H * H2 + 255) / 256, 256, 0, stream>>>(Wc, WcT, H, H2);
    fold_kernel<<<1, 256, 0, stream>>>(Wm, Wl, bm, wmp, wmq, bpq);

    // h0 = bf16(x @ W1 + b1)
    gemm1_mfma<<<nbM, 256, 0, stream>>>(x, W1T, b1, h0_bf, N);
    // agg1 = bf16(A @ h0)
    aggregate_bf16<<<nbW, 256, 0, stream>>>(h0_bf, offs, es, en, dinv, agg1_bf, N);
    // pe,qe = relu(agg1 @ Wc + bc) @ [wmp, wmq]
    gemm2_pq<<<nbM, 512, 0, stream>>>(agg1_bf, WcT, bc, wmp, wmq, pe, qe, N);
    // p,q scalar aggregation
    agg_scalar<<<nbN, 256, 0, stream>>>(pe, qe, offs, es, en, dinv, bpq, p, q, N);
    // out
    edge_out_kernel<<<nbE, 256, 0, stream>>>(src, dst, p, q, bl, out, E);
}

// Round 3
// 278.177 us; speedup vs baseline: 1.9624x; 1.1613x over previous
//
#include <hip/hip_runtime.h>
#include <hip/hip_bf16.h>
#include <math.h>

// GCN link predictor, bf16 MFMA pipeline.
//   CSR build (hist/scan/scatter)
//   h0_bf = bf16(x @ W1 + b1)            [N,128]  MFMA GEMM, reg-prefetch pipelined
//   agg1_bf = bf16(A_norm @ h0_bf)       [N,128]  wave-per-node aggregate, 8-wide MLP
//   pe,qe = relu(agg1 @ Wc + bc) @ [wmp,wmq]      MFMA GEMM fused epilogue
//   p = A_norm @ pe + bm.wp ; q = A_norm @ qe + bm.wq   (scalar aggregate, 4-wide MLP)
//   out[e] = sigmoid(p[src] + q[dst] + bl)

typedef __attribute__((ext_vector_type(8))) short bf16x8;
typedef __attribute__((ext_vector_type(4))) float f32x4;

static __device__ __forceinline__ ushort f2b(float f) {
    __hip_bfloat16 h = __float2bfloat16(f);
    return *(ushort*)&h;
}
static __device__ __forceinline__ float b2f(ushort u) {
    unsigned int v = ((unsigned int)u) << 16;
    return *(float*)&v;
}

// ---------------- CSR build ----------------

__global__ __launch_bounds__(256) void init_kernel(float* deg, int* cnt, int n) {
    int i = blockIdx.x * 256 + threadIdx.x;
    if (i < n) { deg[i] = 1.0f; cnt[i] = 0; }   // self-loop weight 1
}

__global__ __launch_bounds__(256) void hist_kernel(const int* __restrict__ dst,
                                                   const float* __restrict__ w,
                                                   float* deg, int* cnt, int e) {
    int i = blockIdx.x * 256 + threadIdx.x;
    if (i < e) {
        int d = dst[i];
        atomicAdd(&deg[d], w[i]);
        atomicAdd(&cnt[d], 1);
    }
}

__global__ __launch_bounds__(256) void dinv_kernel(const float* __restrict__ deg,
                                                   float* __restrict__ dinv, int n) {
    int i = blockIdx.x * 256 + threadIdx.x;
    if (i < n) {
        float d = deg[i];
        dinv[i] = (d > 0.0f) ? (1.0f / sqrtf(d)) : 0.0f;
    }
}

__global__ __launch_bounds__(1024) void scan_partial(const int* __restrict__ cnt,
                                                     int* __restrict__ offs,
                                                     int* __restrict__ bsum, int n) {
    __shared__ int s[1024];
    int t = threadIdx.x;
    int i = blockIdx.x * 1024 + t;
    int v = (i < n) ? cnt[i] : 0;
    s[t] = v;
    __syncthreads();
    for (int off = 1; off < 1024; off <<= 1) {
        int add = (t >= off) ? s[t - off] : 0;
        __syncthreads();
        s[t] += add;
        __syncthreads();
    }
    if (i < n) offs[i] = s[t] - v;
    if (t == 1023) bsum[blockIdx.x] = s[t];
}

__global__ void scan_bsum(int* bsum, int* offs, int nblk, int n) {
    if (blockIdx.x == 0 && threadIdx.x == 0) {
        int running = 0;
        for (int b = 0; b < nblk; ++b) { int t = bsum[b]; bsum[b] = running; running += t; }
        offs[n] = running;
    }
}

__global__ __launch_bounds__(256) void scan_add(int* __restrict__ offs,
                                                const int* __restrict__ bsum,
                                                int* __restrict__ cursor, int n) {
    int i = blockIdx.x * 256 + threadIdx.x;
    if (i < n) {
        int v = offs[i] + bsum[i >> 10];
        offs[i] = v;
        cursor[i] = v;
    }
}

__global__ __launch_bounds__(256) void scatter_kernel(const int* __restrict__ src,
                                                      const int* __restrict__ dst,
                                                      const float* __restrict__ w,
                                                      const float* __restrict__ dinv,
                                                      int* cursor,
                                                      int* __restrict__ es,
                                                      float* __restrict__ en, int e) {
    int i = blockIdx.x * 256 + threadIdx.x;
    if (i < e) {
        int s = src[i], d = dst[i];
        float nrm = dinv[s] * w[i] * dinv[d];
        int pos = atomicAdd(&cursor[d], 1);
        es[pos] = s;
        en[pos] = nrm;
    }
}

// ---------------- weight prep ----------------

// BT[n][k] = bf16(B[k][n])
__global__ __launch_bounds__(256) void tconv_kernel(const float* __restrict__ B,
                                                    ushort* __restrict__ BT, int K, int Nn) {
    int i = blockIdx.x * 256 + threadIdx.x;
    if (i < K * Nn) {
        int k = i / Nn, n = i % Nn;
        BT[(size_t)n * K + k] = f2b(B[i]);
    }
}

// wmp = Wm @ Wl[:128], wmq = Wm @ Wl[128:], bpq = {bm.wp, bm.wq}
__global__ __launch_bounds__(256) void fold_kernel(const float* __restrict__ Wm,
                                                   const float* __restrict__ Wl,
                                                   const float* __restrict__ bm,
                                                   float* __restrict__ wmp,
                                                   float* __restrict__ wmq,
                                                   float* __restrict__ bpq) {
    int j = threadIdx.x;
    float sp = 0.f, sq = 0.f;
    for (int k = 0; k < 128; ++k) {
        float v = Wm[(size_t)j * 128 + k];
        sp += v * Wl[k];
        sq += v * Wl[128 + k];
    }
    wmp[j] = sp; wmq[j] = sq;
    if (j == 0) { float s = 0.f; for (int k = 0; k < 128; ++k) s += bm[k] * Wl[k];       bpq[0] = s; }
    if (j == 1) { float s = 0.f; for (int k = 0; k < 128; ++k) s += bm[k] * Wl[128 + k]; bpq[1] = s; }
}

// ---------------- GEMM1: h0_bf = bf16(x @ W1 + b1) ----------------
// BM=128, BN=128(full), K=512, BK=64. 256 threads = 4 waves (2x2), wave tile 64x64.
// Reg-prefetch pipeline: loads for tile t+1 issued before barrier of tile t.
__global__ __launch_bounds__(256) void gemm1_mfma(const float* __restrict__ A,
                                                  const ushort* __restrict__ BT,  // [128][512] bf16
                                                  const float* __restrict__ bias,
                                                  ushort* __restrict__ C, int M) {
    __shared__ ushort As[128 * 64];
    __shared__ ushort Bs[128 * 64];
    const int t = threadIdx.x;
    const int bm = blockIdx.x * 128;
    const int lane = t & 63;
    const int wid = t >> 6;
    const int wm = (wid >> 1) * 64, wn = (wid & 1) * 64;

    f32x4 acc[4][4] = {};

    // A staging map: j in 0..7 -> row = wid*32 + j*4 + (lane>>4), col = (lane&15)*4
    //   16 lanes cover one full 64-float k-slice (256B contiguous per row).
    const int arow0 = wid * 32 + (lane >> 4);
    const int acol  = (lane & 15) * 4;
    // B staging map: j in 0..3 -> row = wid*32 + j*8 + (lane>>3), col = (lane&7)*8
    //   8 lanes cover one full 64-bf16 k-slice (128B contiguous per row).
    const int brow0 = wid * 32 + (lane >> 3);
    const int bcol  = (lane & 7) * 8;

    float4 aReg[8];
    uint4  bReg[4];

    auto issue = [&](int k0) {
#pragma unroll
        for (int j = 0; j < 8; ++j) {
            int row = arow0 + j * 4;
            bool valid = (bm + row) < M;
            aReg[j] = valid ? *(const float4*)(A + (size_t)(bm + row) * 512 + k0 + acol)
                            : make_float4(0.f, 0.f, 0.f, 0.f);
        }
#pragma unroll
        for (int j = 0; j < 4; ++j) {
            int row = brow0 + j * 8;
            bReg[j] = *(const uint4*)(BT + (size_t)row * 512 + k0 + bcol);
        }
    };

    issue(0);

#pragma unroll 1
    for (int tt = 0; tt < 8; ++tt) {
        // convert + write to LDS (consumes regs; compiler inserts vmcnt wait here)
#pragma unroll
        for (int j = 0; j < 8; ++j) {
            int row = arow0 + j * 4;
            ushort4 u;
            u.x = f2b(aReg[j].x); u.y = f2b(aReg[j].y); u.z = f2b(aReg[j].z); u.w = f2b(aReg[j].w);
            int byte = (row * 128 + acol * 2) ^ ((row & 7) << 4);
            *(ushort4*)((char*)As + byte) = u;
        }
#pragma unroll
        for (int j = 0; j < 4; ++j) {
            int row = brow0 + j * 8;
            int byte = (row * 128 + bcol * 2) ^ ((row & 7) << 4);
            *(uint4*)((char*)Bs + byte) = bReg[j];
        }
        if (tt < 7) issue((tt + 1) * 64);   // in flight across the MFMA phase
        __syncthreads();
#pragma unroll
        for (int ks = 0; ks < 2; ++ks) {
            bf16x8 af[4], bfr[4];
#pragma unroll
            for (int mi = 0; mi < 4; ++mi) {
                int row = wm + mi * 16 + (lane & 15);
                int byte = (row * 128 + ks * 64 + (lane >> 4) * 16) ^ ((row & 7) << 4);
                af[mi] = *(bf16x8*)((char*)As + byte);
            }
#pragma unroll
            for (int ni = 0; ni < 4; ++ni) {
                int row = wn + ni * 16 + (lane & 15);
                int byte = (row * 128 + ks * 64 + (lane >> 4) * 16) ^ ((row & 7) << 4);
                bfr[ni] = *(bf16x8*)((char*)Bs + byte);
            }
#pragma unroll
            for (int mi = 0; mi < 4; ++mi)
#pragma unroll
                for (int ni = 0; ni < 4; ++ni)
                    acc[mi][ni] = __builtin_amdgcn_mfma_f32_16x16x32_bf16(af[mi], bfr[ni], acc[mi][ni], 0, 0, 0);
        }
        __syncthreads();
    }
    // epilogue: + bias, -> bf16
#pragma unroll
    for (int ni = 0; ni < 4; ++ni) {
        int col = wn + ni * 16 + (lane & 15);
        float bv = bias[col];
#pragma unroll
        for (int mi = 0; mi < 4; ++mi)
#pragma unroll
            for (int r = 0; r < 4; ++r) {
                int row = bm + wm + mi * 16 + (lane >> 4) * 4 + r;
                if (row < M) C[(size_t)row * 128 + col] = f2b(acc[mi][ni][r] + bv);
            }
    }
}

// ---------------- aggregate (bf16 in/out), 8-wide MLP ----------------
// out[i] = dinv[i]^2*h[i] + sum norm*h[es]; one wave per node, uint (2 bf16) per lane.
__global__ __launch_bounds__(256) void aggregate_bf16(const ushort* __restrict__ h,
                                                      const int* __restrict__ offs,
                                                      const int* __restrict__ es,
                                                      const float* __restrict__ en,
                                                      const float* __restrict__ dinv,
                                                      ushort* __restrict__ out, int n) {
    int wave = (int)((blockIdx.x * (size_t)blockDim.x + threadIdx.x) >> 6);
    int lane = threadIdx.x & 63;
    if (wave >= n) return;
    float di = dinv[wave];
    float sw = di * di;
    unsigned int hv = *(const unsigned int*)(h + (size_t)wave * 128 + lane * 2);
    float ax = sw * b2f((ushort)(hv & 0xffff));
    float ay = sw * b2f((ushort)(hv >> 16));
    int beg = offs[wave], end = offs[wave + 1];
    for (int e = beg; e < end; e += 8) {
        int sx[8]; float wx[8];
#pragma unroll
        for (int j = 0; j < 8; ++j) {
            bool v = (e + j) < end;
            sx[j] = v ? es[e + j] : wave;      // padded: self row (L1-hot), weight 0
            wx[j] = v ? en[e + j] : 0.f;
        }
        unsigned int vv[8];
#pragma unroll
        for (int j = 0; j < 8; ++j)
            vv[j] = *(const unsigned int*)(h + (size_t)sx[j] * 128 + lane * 2);
#pragma unroll
        for (int j = 0; j < 8; ++j) {
            ax += wx[j] * b2f((ushort)(vv[j] & 0xffff));
            ay += wx[j] * b2f((ushort)(vv[j] >> 16));
        }
    }
    unsigned int o = (unsigned int)f2b(ax) | ((unsigned int)f2b(ay) << 16);
    *(unsigned int*)(out + (size_t)wave * 128 + lane * 2) = o;
}

// ---------------- GEMM2 fused: pe,qe = relu(agg1@Wc + bc) @ [wmp,wmq] ----------------
// BM=128, BN=256(full), K=128, BK=64. 512 threads = 8 waves (2M x 4N), wave tile 64x64.
__global__ __launch_bounds__(512) void gemm2_pq(const ushort* __restrict__ A,   // [M][128] bf16
                                                const ushort* __restrict__ BT,  // [256][128] bf16
                                                const float* __restrict__ bc,
                                                const float* __restrict__ wmp,
                                                const float* __restrict__ wmq,
                                                float* __restrict__ pe,
                                                float* __restrict__ qe, int M) {
    __shared__ ushort As[128 * 64];
    __shared__ ushort Bs[256 * 64];
    __shared__ float partp[4][128];
    __shared__ float partq[4][128];
    const int t = threadIdx.x;
    const int bm = blockIdx.x * 128;
    const int lane = t & 63;
    const int wid = t >> 6;
    const int wm = (wid >> 2) * 64, wn = (wid & 3) * 64;

    f32x4 acc[4][4] = {};

    // A staging: j in 0..1 -> row = wid*16 + j*8 + (lane>>3), col = (lane&7)*8
    const int arow0 = wid * 16 + (lane >> 3);
    // B staging: j in 0..3 -> row = wid*32 + j*8 + (lane>>3), col = (lane&7)*8
    const int brow0 = wid * 32 + (lane >> 3);
    const int ccol  = (lane & 7) * 8;

    uint4 aReg[2];
    uint4 bReg[4];

    auto issue = [&](int k0) {
#pragma unroll
        for (int j = 0; j < 2; ++j) {
            int row = arow0 + j * 8;
            bool valid = (bm + row) < M;
            aReg[j] = valid ? *(const uint4*)(A + (size_t)(bm + row) * 128 + k0 + ccol)
                            : make_uint4(0, 0, 0, 0);
        }
#pragma unroll
        for (int j = 0; j < 4; ++j) {
            int row = brow0 + j * 8;
            bReg[j] = *(const uint4*)(BT + (size_t)row * 128 + k0 + ccol);
        }
    };

    issue(0);

#pragma unroll 1
    for (int tt = 0; tt < 2; ++tt) {
#pragma unroll
        for (int j = 0; j < 2; ++j) {
            int row = arow0 + j * 8;
            int byte = (row * 128 + ccol * 2) ^ ((row & 7) << 4);
            *(uint4*)((char*)As + byte) = aReg[j];
        }
#pragma unroll
        for (int j = 0; j < 4; ++j) {
            int row = brow0 + j * 8;
            int byte = (row * 128 + ccol * 2) ^ ((row & 7) << 4);
            *(uint4*)((char*)Bs + byte) = bReg[j];
        }
        if (tt < 1) issue(64);
        __syncthreads();
#pragma unroll
        for (int ks = 0; ks < 2; ++ks) {
            bf16x8 af[4], bfr[4];
#pragma unroll
            for (int mi = 0; mi < 4; ++mi) {
                int row = wm + mi * 16 + (lane & 15);
                int byte = (row * 128 + ks * 64 + (lane >> 4) * 16) ^ ((row & 7) << 4);
                af[mi] = *(bf16x8*)((char*)As + byte);
            }
#pragma unroll
            for (int ni = 0; ni < 4; ++ni) {
                int row = wn + ni * 16 + (lane & 15);
                int byte = (row * 128 + ks * 64 + (lane >> 4) * 16) ^ ((row & 7) << 4);
                bfr[ni] = *(bf16x8*)((char*)Bs + byte);
            }
#pragma unroll
            for (int mi = 0; mi < 4; ++mi)
#pragma unroll
                for (int ni = 0; ni < 4; ++ni)
                    acc[mi][ni] = __builtin_amdgcn_mfma_f32_16x16x32_bf16(af[mi], bfr[ni], acc[mi][ni], 0, 0, 0);
        }
        __syncthreads();
    }

    // epilogue: bias + relu + dot with wmp/wmq, reduce over N
    float bcv[4], wpv[4], wqv[4];
#pragma unroll
    for (int ni = 0; ni < 4; ++ni) {
        int col = wn + ni * 16 + (lane & 15);
        bcv[ni] = bc[col];
        wpv[ni] = wmp[col];
        wqv[ni] = wmq[col];
    }
#pragma unroll
    for (int mi = 0; mi < 4; ++mi) {
#pragma unroll
        for (int r = 0; r < 4; ++r) {
            float sp = 0.f, sq = 0.f;
#pragma unroll
            for (int ni = 0; ni < 4; ++ni) {
                float h = fmaxf(acc[mi][ni][r] + bcv[ni], 0.f);
                sp += h * wpv[ni];
                sq += h * wqv[ni];
            }
#pragma unroll
            for (int off = 1; off < 16; off <<= 1) {
                sp += __shfl_xor(sp, off);
                sq += __shfl_xor(sq, off);
            }
            if ((lane & 15) == 0) {
                int row = wm + mi * 16 + (lane >> 4) * 4 + r;   // 0..127
                partp[wid & 3][row] = sp;
                partq[wid & 3][row] = sq;
            }
        }
    }
    __syncthreads();
    if (t < 128) {
        int row = t;
        if (bm + row < M)
            pe[bm + row] = partp[0][row] + partp[1][row] + partp[2][row] + partp[3][row];
    } else if (t < 256) {
        int row = t - 128;
        if (bm + row < M)
            qe[bm + row] = partq[0][row] + partq[1][row] + partq[2][row] + partq[3][row];
    }
}

// ---------------- scalar aggregation: p = A@pe + bp, q = A@qe + bq (4-wide MLP) ----------------
__global__ __launch_bounds__(256) void agg_scalar(const float* __restrict__ pe,
                                                  const float* __restrict__ qe,
                                                  const int* __restrict__ offs,
                                                  const int* __restrict__ es,
                                                  const float* __restrict__ en,
                                                  const float* __restrict__ dinv,
                                                  const float* __restrict__ bpq,
                                                  float* __restrict__ p,
                                                  float* __restrict__ q, int n) {
    int i = blockIdx.x * 256 + threadIdx.x;
    if (i >= n) return;
    float di = dinv[i];
    float sw = di * di;
    float ap = sw * pe[i], aq = sw * qe[i];
    int beg = offs[i], end = offs[i + 1];
    for (int k = beg; k < end; k += 4) {
        int sx[4]; float wx[4];
#pragma unroll
        for (int j = 0; j < 4; ++j) {
            bool v = (k + j) < end;
            sx[j] = v ? es[k + j] : i;
            wx[j] = v ? en[k + j] : 0.f;
        }
        float pv[4], qv[4];
#pragma unroll
        for (int j = 0; j < 4; ++j) { pv[j] = pe[sx[j]]; qv[j] = qe[sx[j]]; }
#pragma unroll
        for (int j = 0; j < 4; ++j) { ap += wx[j] * pv[j]; aq += wx[j] * qv[j]; }
    }
    p[i] = ap + bpq[0];
    q[i] = aq + bpq[1];
}

__global__ __launch_bounds__(256) void edge_out_kernel(const int* __restrict__ src,
                                                       const int* __restrict__ dst,
                                                       const float* __restrict__ p,
                                                       const float* __restrict__ q,
                                                       const float* __restrict__ bl,
                                                       float* __restrict__ out, int e) {
    int i = blockIdx.x * 256 + threadIdx.x;
    if (i < e) {
        float t = p[src[i]] + q[dst[i]] + bl[0];
        out[i] = 1.0f / (1.0f + expf(-t));
    }
}

// ---------------- launch ----------------

extern "C" void kernel_launch(void* const* d_in, const int* in_sizes, int n_in,
                              void* d_out, int out_size, void* d_ws, size_t ws_size,
                              hipStream_t stream) {
    const int*   edge_index = (const int*)d_in[0];
    const float* x   = (const float*)d_in[1];
    const float* w   = (const float*)d_in[2];
    const float* W1  = (const float*)d_in[3];
    const float* b1  = (const float*)d_in[4];
    const float* Wc  = (const float*)d_in[5];
    const float* bc  = (const float*)d_in[6];
    const float* Wm  = (const float*)d_in[7];
    const float* bm  = (const float*)d_in[8];
    const float* Wl  = (const float*)d_in[9];
    const float* bl  = (const float*)d_in[10];
    float* out = (float*)d_out;

    const int E  = in_sizes[2];            // 800000
    const int H  = in_sizes[4];            // 128
    const int F  = in_sizes[3] / H;        // 512
    const int N  = in_sizes[1] / F;        // 50000
    const int H2 = 2 * H;                  // 256

    const int* src = edge_index;
    const int* dst = edge_index + E;

    char* ws = (char*)d_ws;
    size_t off = 0;
    auto alloc = [&](size_t bytes) -> void* {
        off = (off + 255) & ~(size_t)255;
        void* r = ws + off;
        off += bytes;
        return r;
    };
    float*  deg     = (float*) alloc((size_t)N * 4);
    float*  dinv    = (float*) alloc((size_t)N * 4);
    int*    cnt     = (int*)   alloc((size_t)N * 4);
    int*    offs    = (int*)   alloc((size_t)(N + 1) * 4);
    int*    cursor  = (int*)   alloc((size_t)N * 4);
    int*    bsum    = (int*)   alloc(256 * 4);
    int*    es      = (int*)   alloc((size_t)E * 4);
    float*  en      = (float*) alloc((size_t)E * 4);
    ushort* h0_bf   = (ushort*)alloc((size_t)N * H * 2);
    ushort* agg1_bf = (ushort*)alloc((size_t)N * H * 2);
    ushort* W1T     = (ushort*)alloc((size_t)H * F * 2);   // [128][512]
    ushort* WcT     = (ushort*)alloc((size_t)H2 * H * 2);  // [256][128]
    float*  wmp     = (float*) alloc(H2 * 4);
    float*  wmq     = (float*) alloc(H2 * 4);
    float*  bpq     = (float*) alloc(2 * 4);
    float*  pe      = (float*) alloc((size_t)N * 4);
    float*  qe      = (float*) alloc((size_t)N * 4);
    float*  p       = (float*) alloc((size_t)N * 4);
    float*  q       = (float*) alloc((size_t)N * 4);
    (void)ws_size; (void)n_in; (void)out_size;

    int nbN  = (N + 255) / 256;
    int nbE  = (E + 255) / 256;
    int nblk = (N + 1023) / 1024;
    int nbW  = (int)(((size_t)N * 64 + 255) / 256);
    int nbM  = (N + 127) / 128;

    // CSR build
    init_kernel<<<nbN, 256, 0, stream>>>(deg, cnt, N);
    hist_kernel<<<nbE, 256, 0, stream>>>(dst, w, deg, cnt, E);
    dinv_kernel<<<nbN, 256, 0, stream>>>(deg, dinv, N);
    scan_partial<<<nblk, 1024, 0, stream>>>(cnt, offs, bsum, N);
    scan_bsum<<<1, 1, 0, stream>>>(bsum, offs, nblk, N);
    scan_add<<<nbN, 256, 0, stream>>>(offs, bsum, cursor, N);
    scatter_kernel<<<nbE, 256, 0, stream>>>(src, dst, w, dinv, cursor, es, en, E);

    // weight prep (independent of CSR; cheap)
    tconv_kernel<<<(F * H + 255) / 256, 256, 0, stream>>>(W1, W1T, F, H);
    tconv_kernel<<<(H * H2 + 255) / 256, 256, 0, stream>>>(Wc, WcT, H, H2);
    fold_kernel<<<1, 256, 0, stream>>>(Wm, Wl, bm, wmp, wmq, bpq);

    // h0 = bf16(x @ W1 + b1)
    gemm1_mfma<<<nbM, 256, 0, stream>>>(x, W1T, b1, h0_bf, N);
    // agg1 = bf16(A @ h0)
    aggregate_bf16<<<nbW, 256, 0, stream>>>(h0_bf, offs, es, en, dinv, agg1_bf, N);
    // pe,qe = relu(agg1 @ Wc + bc) @ [wmp, wmq]
    gemm2_pq<<<nbM, 512, 0, stream>>>(agg1_bf, WcT, bc, wmp, wmq, pe, qe, N);
    // p,q scalar aggregation
    agg_scalar<<<nbN, 256, 0, stream>>>(pe, qe, offs, es, en, dinv, bpq, p, q, N);
    // out
    edge_out_kernel<<<nbE, 256, 0, stream>>>(src, dst, p, q, bl, out, E);
}

// Round 4
// 274.185 us; speedup vs baseline: 1.9909x; 1.0146x over previous
//
#include <hip/hip_runtime.h>
#include <hip/hip_bf16.h>
#include <math.h>

// GCN link predictor, bf16 MFMA pipeline, atomic-free CSR build.
//   P1 part_hist: per (range,slice) LDS histograms (cnt + weighted deg)
//   P2 reduce_part: cnt/deg/dinv + exclusive prefix over slices (cursor bases)
//   scan: offs
//   P3 csr_scatter: LDS cursors -> es/en (no global atomics)
//   h0_bf = bf16(x @ W1 + b1)            [N,128]  MFMA GEMM, reg-prefetch pipelined
//   agg1_bf = bf16(A_norm @ h0_bf)       [N,128]  wave-per-node aggregate, 8-wide MLP
//   pe,qe = relu(agg1 @ Wc + bc) @ [wmp,wmq]      MFMA GEMM fused epilogue
//   p = A_norm @ pe + bm.wp ; q = A_norm @ qe + bm.wq   (scalar aggregate, 4-wide MLP)
//   out[e] = sigmoid(p[src] + q[dst] + bl)

#define NRANGE 8
#define NSLICE 32
#define MAXRANGE 6272   // LDS array size; RANGE = ceil(N/NRANGE) must be <= this

typedef __attribute__((ext_vector_type(8))) short bf16x8;
typedef __attribute__((ext_vector_type(4))) float f32x4;

static __device__ __forceinline__ ushort f2b(float f) {
    __hip_bfloat16 h = __float2bfloat16(f);
    return *(ushort*)&h;
}
static __device__ __forceinline__ float b2f(ushort u) {
    unsigned int v = ((unsigned int)u) << 16;
    return *(float*)&v;
}

// ---------------- P1: partial histograms (LDS atomics only) ----------------
__global__ __launch_bounds__(256) void part_hist(const int* __restrict__ dst,
                                                 const float* __restrict__ w,
                                                 int* __restrict__ pc,
                                                 float* __restrict__ pw,
                                                 int E, int N, int RANGE) {
    __shared__ int   lc[MAXRANGE];
    __shared__ float lw[MAXRANGE];
    const int b = blockIdx.x, r = blockIdx.y;
    const int t = threadIdx.x;
    const int base = r * RANGE;
    const int rs = min(RANGE, N - base);
    for (int i = t; i < rs; i += 256) { lc[i] = 0; lw[i] = 0.f; }
    __syncthreads();
    const int beg = (int)((size_t)b * E / NSLICE);
    const int end = (int)((size_t)(b + 1) * E / NSLICE);
    for (int e = beg + t; e < end; e += 256) {
        int d = dst[e];
        int il = d - base;
        if ((unsigned)il < (unsigned)rs) {
            atomicAdd(&lc[il], 1);
            atomicAdd(&lw[il], w[e]);
        }
    }
    __syncthreads();
    int* pco = pc + (size_t)(r * NSLICE + b) * RANGE;
    float* pwo = pw + (size_t)(r * NSLICE + b) * RANGE;
    for (int i = t; i < rs; i += 256) { pco[i] = lc[i]; pwo[i] = lw[i]; }
}

// ---------------- P2: reduce partials -> cnt, dinv; in-place exclusive prefix ----------------
__global__ __launch_bounds__(256) void reduce_part(int* __restrict__ pc,
                                                   const float* __restrict__ pw,
                                                   int* __restrict__ cnt,
                                                   float* __restrict__ dinv,
                                                   int N, int RANGE) {
    int node = blockIdx.x * 256 + threadIdx.x;
    if (node >= N) return;
    int r = node / RANGE;
    int il = node - r * RANGE;
    int run = 0;
    float ws = 0.f;
#pragma unroll 4
    for (int b = 0; b < NSLICE; ++b) {
        size_t idx = (size_t)(r * NSLICE + b) * RANGE + il;
        int c = pc[idx];
        pc[idx] = run;        // exclusive prefix over slices
        run += c;
        ws += pw[idx];
    }
    cnt[node] = run;
    float d = 1.0f + ws;      // self-loop weight 1; d >= 1
    dinv[node] = 1.0f / sqrtf(d);
}

// ---------------- scan over cnt -> offs ----------------
__global__ __launch_bounds__(1024) void scan_partial(const int* __restrict__ cnt,
                                                     int* __restrict__ offs,
                                                     int* __restrict__ bsum, int n) {
    __shared__ int s[1024];
    int t = threadIdx.x;
    int i = blockIdx.x * 1024 + t;
    int v = (i < n) ? cnt[i] : 0;
    s[t] = v;
    __syncthreads();
    for (int off = 1; off < 1024; off <<= 1) {
        int add = (t >= off) ? s[t - off] : 0;
        __syncthreads();
        s[t] += add;
        __syncthreads();
    }
    if (i < n) offs[i] = s[t] - v;
    if (t == 1023) bsum[blockIdx.x] = s[t];
}

__global__ void scan_bsum(int* bsum, int* offs, int nblk, int n) {
    if (blockIdx.x == 0 && threadIdx.x == 0) {
        int running = 0;
        for (int b = 0; b < nblk; ++b) { int t = bsum[b]; bsum[b] = running; running += t; }
        offs[n] = running;
    }
}

__global__ __launch_bounds__(256) void scan_add(int* __restrict__ offs,
                                                const int* __restrict__ bsum, int n) {
    int i = blockIdx.x * 256 + threadIdx.x;
    if (i < n) offs[i] += bsum[i >> 10];
}

// ---------------- P3: scatter into CSR via LDS cursors ----------------
__global__ __launch_bounds__(256) void csr_scatter(const int* __restrict__ src,
                                                   const int* __restrict__ dst,
                                                   const float* __restrict__ w,
                                                   const float* __restrict__ dinv,
                                                   const int* __restrict__ offs,
                                                   const int* __restrict__ pc,
                                                   int* __restrict__ es,
                                                   float* __restrict__ en,
                                                   int E, int N, int RANGE) {
    __shared__ int cur[MAXRANGE];
    const int b = blockIdx.x, r = blockIdx.y;
    const int t = threadIdx.x;
    const int base = r * RANGE;
    const int rs = min(RANGE, N - base);
    const int* pci = pc + (size_t)(r * NSLICE + b) * RANGE;
    for (int i = t; i < rs; i += 256) cur[i] = offs[base + i] + pci[i];
    __syncthreads();
    const int beg = (int)((size_t)b * E / NSLICE);
    const int end = (int)((size_t)(b + 1) * E / NSLICE);
    for (int e = beg + t; e < end; e += 256) {
        int d = dst[e];
        int il = d - base;
        if ((unsigned)il < (unsigned)rs) {
            int s = src[e];
            int pos = atomicAdd(&cur[il], 1);
            es[pos] = s;
            en[pos] = dinv[s] * w[e] * dinv[d];
        }
    }
}

// ---------------- weight prep ----------------

// BT[n][k] = bf16(B[k][n])
__global__ __launch_bounds__(256) void tconv_kernel(const float* __restrict__ B,
                                                    ushort* __restrict__ BT, int K, int Nn) {
    int i = blockIdx.x * 256 + threadIdx.x;
    if (i < K * Nn) {
        int k = i / Nn, n = i % Nn;
        BT[(size_t)n * K + k] = f2b(B[i]);
    }
}

// wmp = Wm @ Wl[:128], wmq = Wm @ Wl[128:], bpq = {bm.wp, bm.wq}
__global__ __launch_bounds__(256) void fold_kernel(const float* __restrict__ Wm,
                                                   const float* __restrict__ Wl,
                                                   const float* __restrict__ bm,
                                                   float* __restrict__ wmp,
                                                   float* __restrict__ wmq,
                                                   float* __restrict__ bpq) {
    int j = threadIdx.x;
    float sp = 0.f, sq = 0.f;
    for (int k = 0; k < 128; ++k) {
        float v = Wm[(size_t)j * 128 + k];
        sp += v * Wl[k];
        sq += v * Wl[128 + k];
    }
    wmp[j] = sp; wmq[j] = sq;
    if (j == 0) { float s = 0.f; for (int k = 0; k < 128; ++k) s += bm[k] * Wl[k];       bpq[0] = s; }
    if (j == 1) { float s = 0.f; for (int k = 0; k < 128; ++k) s += bm[k] * Wl[128 + k]; bpq[1] = s; }
}

// ---------------- GEMM1: h0_bf = bf16(x @ W1 + b1) ----------------
// BM=128, BN=128(full), K=512, BK=64. 256 threads = 4 waves (2x2), wave tile 64x64.
__global__ __launch_bounds__(256) void gemm1_mfma(const float* __restrict__ A,
                                                  const ushort* __restrict__ BT,  // [128][512] bf16
                                                  const float* __restrict__ bias,
                                                  ushort* __restrict__ C, int M) {
    __shared__ ushort As[128 * 64];
    __shared__ ushort Bs[128 * 64];
    const int t = threadIdx.x;
    const int bm = blockIdx.x * 128;
    const int lane = t & 63;
    const int wid = t >> 6;
    const int wm = (wid >> 1) * 64, wn = (wid & 1) * 64;

    f32x4 acc[4][4] = {};

    const int arow0 = wid * 32 + (lane >> 4);
    const int acol  = (lane & 15) * 4;
    const int brow0 = wid * 32 + (lane >> 3);
    const int bcol  = (lane & 7) * 8;

    float4 aReg[8];
    uint4  bReg[4];

    auto issue = [&](int k0) {
#pragma unroll
        for (int j = 0; j < 8; ++j) {
            int row = arow0 + j * 4;
            bool valid = (bm + row) < M;
            aReg[j] = valid ? *(const float4*)(A + (size_t)(bm + row) * 512 + k0 + acol)
                            : make_float4(0.f, 0.f, 0.f, 0.f);
        }
#pragma unroll
        for (int j = 0; j < 4; ++j) {
            int row = brow0 + j * 8;
            bReg[j] = *(const uint4*)(BT + (size_t)row * 512 + k0 + bcol);
        }
    };

    issue(0);

#pragma unroll 1
    for (int tt = 0; tt < 8; ++tt) {
#pragma unroll
        for (int j = 0; j < 8; ++j) {
            int row = arow0 + j * 4;
            ushort4 u;
            u.x = f2b(aReg[j].x); u.y = f2b(aReg[j].y); u.z = f2b(aReg[j].z); u.w = f2b(aReg[j].w);
            int byte = (row * 128 + acol * 2) ^ ((row & 7) << 4);
            *(ushort4*)((char*)As + byte) = u;
        }
#pragma unroll
        for (int j = 0; j < 4; ++j) {
            int row = brow0 + j * 8;
            int byte = (row * 128 + bcol * 2) ^ ((row & 7) << 4);
            *(uint4*)((char*)Bs + byte) = bReg[j];
        }
        if (tt < 7) issue((tt + 1) * 64);
        __syncthreads();
#pragma unroll
        for (int ks = 0; ks < 2; ++ks) {
            bf16x8 af[4], bfr[4];
#pragma unroll
            for (int mi = 0; mi < 4; ++mi) {
                int row = wm + mi * 16 + (lane & 15);
                int byte = (row * 128 + ks * 64 + (lane >> 4) * 16) ^ ((row & 7) << 4);
                af[mi] = *(bf16x8*)((char*)As + byte);
            }
#pragma unroll
            for (int ni = 0; ni < 4; ++ni) {
                int row = wn + ni * 16 + (lane & 15);
                int byte = (row * 128 + ks * 64 + (lane >> 4) * 16) ^ ((row & 7) << 4);
                bfr[ni] = *(bf16x8*)((char*)Bs + byte);
            }
#pragma unroll
            for (int mi = 0; mi < 4; ++mi)
#pragma unroll
                for (int ni = 0; ni < 4; ++ni)
                    acc[mi][ni] = __builtin_amdgcn_mfma_f32_16x16x32_bf16(af[mi], bfr[ni], acc[mi][ni], 0, 0, 0);
        }
        __syncthreads();
    }
#pragma unroll
    for (int ni = 0; ni < 4; ++ni) {
        int col = wn + ni * 16 + (lane & 15);
        float bv = bias[col];
#pragma unroll
        for (int mi = 0; mi < 4; ++mi)
#pragma unroll
            for (int r = 0; r < 4; ++r) {
                int row = bm + wm + mi * 16 + (lane >> 4) * 4 + r;
                if (row < M) C[(size_t)row * 128 + col] = f2b(acc[mi][ni][r] + bv);
            }
    }
}

// ---------------- aggregate (bf16 in/out), 8-wide MLP ----------------
__global__ __launch_bounds__(256) void aggregate_bf16(const ushort* __restrict__ h,
                                                      const int* __restrict__ offs,
                                                      const int* __restrict__ es,
                                                      const float* __restrict__ en,
                                                      const float* __restrict__ dinv,
                                                      ushort* __restrict__ out, int n) {
    int wave = (int)((blockIdx.x * (size_t)blockDim.x + threadIdx.x) >> 6);
    int lane = threadIdx.x & 63;
    if (wave >= n) return;
    float di = dinv[wave];
    float sw = di * di;
    unsigned int hv = *(const unsigned int*)(h + (size_t)wave * 128 + lane * 2);
    float ax = sw * b2f((ushort)(hv & 0xffff));
    float ay = sw * b2f((ushort)(hv >> 16));
    int beg = offs[wave], end = offs[wave + 1];
    for (int e = beg; e < end; e += 8) {
        int sx[8]; float wx[8];
#pragma unroll
        for (int j = 0; j < 8; ++j) {
            bool v = (e + j) < end;
            sx[j] = v ? es[e + j] : wave;
            wx[j] = v ? en[e + j] : 0.f;
        }
        unsigned int vv[8];
#pragma unroll
        for (int j = 0; j < 8; ++j)
            vv[j] = *(const unsigned int*)(h + (size_t)sx[j] * 128 + lane * 2);
#pragma unroll
        for (int j = 0; j < 8; ++j) {
            ax += wx[j] * b2f((ushort)(vv[j] & 0xffff));
            ay += wx[j] * b2f((ushort)(vv[j] >> 16));
        }
    }
    unsigned int o = (unsigned int)f2b(ax) | ((unsigned int)f2b(ay) << 16);
    *(unsigned int*)(out + (size_t)wave * 128 + lane * 2) = o;
}

// ---------------- GEMM2 fused: pe,qe = relu(agg1@Wc + bc) @ [wmp,wmq] ----------------
__global__ __launch_bounds__(512) void gemm2_pq(const ushort* __restrict__ A,   // [M][128] bf16
                                                const ushort* __restrict__ BT,  // [256][128] bf16
                                                const float* __restrict__ bc,
                                                const float* __restrict__ wmp,
                                                const float* __restrict__ wmq,
                                                float* __restrict__ pe,
                                                float* __restrict__ qe, int M) {
    __shared__ ushort As[128 * 64];
    __shared__ ushort Bs[256 * 64];
    __shared__ float partp[4][128];
    __shared__ float partq[4][128];
    const int t = threadIdx.x;
    const int bm = blockIdx.x * 128;
    const int lane = t & 63;
    const int wid = t >> 6;
    const int wm = (wid >> 2) * 64, wn = (wid & 3) * 64;

    f32x4 acc[4][4] = {};

    const int arow0 = wid * 16 + (lane >> 3);
    const int brow0 = wid * 32 + (lane >> 3);
    const int ccol  = (lane & 7) * 8;

    uint4 aReg[2];
    uint4 bReg[4];

    auto issue = [&](int k0) {
#pragma unroll
        for (int j = 0; j < 2; ++j) {
            int row = arow0 + j * 8;
            bool valid = (bm + row) < M;
            aReg[j] = valid ? *(const uint4*)(A + (size_t)(bm + row) * 128 + k0 + ccol)
                            : make_uint4(0, 0, 0, 0);
        }
#pragma unroll
        for (int j = 0; j < 4; ++j) {
            int row = brow0 + j * 8;
            bReg[j] = *(const uint4*)(BT + (size_t)row * 128 + k0 + ccol);
        }
    };

    issue(0);

#pragma unroll 1
    for (int tt = 0; tt < 2; ++tt) {
#pragma unroll
        for (int j = 0; j < 2; ++j) {
            int row = arow0 + j * 8;
            int byte = (row * 128 + ccol * 2) ^ ((row & 7) << 4);
            *(uint4*)((char*)As + byte) = aReg[j];
        }
#pragma unroll
        for (int j = 0; j < 4; ++j) {
            int row = brow0 + j * 8;
            int byte = (row * 128 + ccol * 2) ^ ((row & 7) << 4);
            *(uint4*)((char*)Bs + byte) = bReg[j];
        }
        if (tt < 1) issue(64);
        __syncthreads();
#pragma unroll
        for (int ks = 0; ks < 2; ++ks) {
            bf16x8 af[4], bfr[4];
#pragma unroll
            for (int mi = 0; mi < 4; ++mi) {
                int row = wm + mi * 16 + (lane & 15);
                int byte = (row * 128 + ks * 64 + (lane >> 4) * 16) ^ ((row & 7) << 4);
                af[mi] = *(bf16x8*)((char*)As + byte);
            }
#pragma unroll
            for (int ni = 0; ni < 4; ++ni) {
                int row = wn + ni * 16 + (lane & 15);
                int byte = (row * 128 + ks * 64 + (lane >> 4) * 16) ^ ((row & 7) << 4);
                bfr[ni] = *(bf16x8*)((char*)Bs + byte);
            }
#pragma unroll
            for (int mi = 0; mi < 4; ++mi)
#pragma unroll
                for (int ni = 0; ni < 4; ++ni)
                    acc[mi][ni] = __builtin_amdgcn_mfma_f32_16x16x32_bf16(af[mi], bfr[ni], acc[mi][ni], 0, 0, 0);
        }
        __syncthreads();
    }

    float bcv[4], wpv[4], wqv[4];
#pragma unroll
    for (int ni = 0; ni < 4; ++ni) {
        int col = wn + ni * 16 + (lane & 15);
        bcv[ni] = bc[col];
        wpv[ni] = wmp[col];
        wqv[ni] = wmq[col];
    }
#pragma unroll
    for (int mi = 0; mi < 4; ++mi) {
#pragma unroll
        for (int r = 0; r < 4; ++r) {
            float sp = 0.f, sq = 0.f;
#pragma unroll
            for (int ni = 0; ni < 4; ++ni) {
                float h = fmaxf(acc[mi][ni][r] + bcv[ni], 0.f);
                sp += h * wpv[ni];
                sq += h * wqv[ni];
            }
#pragma unroll
            for (int off = 1; off < 16; off <<= 1) {
                sp += __shfl_xor(sp, off);
                sq += __shfl_xor(sq, off);
            }
            if ((lane & 15) == 0) {
                int row = wm + mi * 16 + (lane >> 4) * 4 + r;
                partp[wid & 3][row] = sp;
                partq[wid & 3][row] = sq;
            }
        }
    }
    __syncthreads();
    if (t < 128) {
        int row = t;
        if (bm + row < M)
            pe[bm + row] = partp[0][row] + partp[1][row] + partp[2][row] + partp[3][row];
    } else if (t < 256) {
        int row = t - 128;
        if (bm + row < M)
            qe[bm + row] = partq[0][row] + partq[1][row] + partq[2][row] + partq[3][row];
    }
}

// ---------------- scalar aggregation: p = A@pe + bp, q = A@qe + bq (4-wide MLP) ----------------
__global__ __launch_bounds__(256) void agg_scalar(const float* __restrict__ pe,
                                                  const float* __restrict__ qe,
                                                  const int* __restrict__ offs,
                                                  const int* __restrict__ es,
                                                  const float* __restrict__ en,
                                                  const float* __restrict__ dinv,
                                                  const float* __restrict__ bpq,
                                                  float* __restrict__ p,
                                                  float* __restrict__ q, int n) {
    int i = blockIdx.x * 256 + threadIdx.x;
    if (i >= n) return;
    float di = dinv[i];
    float sw = di * di;
    float ap = sw * pe[i], aq = sw * qe[i];
    int beg = offs[i], end = offs[i + 1];
    for (int k = beg; k < end; k += 4) {
        int sx[4]; float wx[4];
#pragma unroll
        for (int j = 0; j < 4; ++j) {
            bool v = (k + j) < end;
            sx[j] = v ? es[k + j] : i;
            wx[j] = v ? en[k + j] : 0.f;
        }
        float pv[4], qv[4];
#pragma unroll
        for (int j = 0; j < 4; ++j) { pv[j] = pe[sx[j]]; qv[j] = qe[sx[j]]; }
#pragma unroll
        for (int j = 0; j < 4; ++j) { ap += wx[j] * pv[j]; aq += wx[j] * qv[j]; }
    }
    p[i] = ap + bpq[0];
    q[i] = aq + bpq[1];
}

__global__ __launch_bounds__(256) void edge_out_kernel(const int* __restrict__ src,
                                                       const int* __restrict__ dst,
                                                       const float* __restrict__ p,
                                                       const float* __restrict__ q,
                                                       const float* __restrict__ bl,
                                                       float* __restrict__ out, int e) {
    int i = blockIdx.x * 256 + threadIdx.x;
    if (i < e) {
        float t = p[src[i]] + q[dst[i]] + bl[0];
        out[i] = 1.0f / (1.0f + expf(-t));
    }
}

// ---------------- launch ----------------

extern "C" void kernel_launch(void* const* d_in, const int* in_sizes, int n_in,
                              void* d_out, int out_size, void* d_ws, size_t ws_size,
                              hipStream_t stream) {
    const int*   edge_index = (const int*)d_in[0];
    const float* x   = (const float*)d_in[1];
    const float* w   = (const float*)d_in[2];
    const float* W1  = (const float*)d_in[3];
    const float* b1  = (const float*)d_in[4];
    const float* Wc  = (const float*)d_in[5];
    const float* bc  = (const float*)d_in[6];
    const float* Wm  = (const float*)d_in[7];
    const float* bm  = (const float*)d_in[8];
    const float* Wl  = (const float*)d_in[9];
    const float* bl  = (const float*)d_in[10];
    float* out = (float*)d_out;

    const int E  = in_sizes[2];            // 800000
    const int H  = in_sizes[4];            // 128
    const int F  = in_sizes[3] / H;        // 512
    const int N  = in_sizes[1] / F;        // 50000
    const int H2 = 2 * H;                  // 256
    const int RANGE = (N + NRANGE - 1) / NRANGE;   // 6250 (<= MAXRANGE)

    const int* src = edge_index;
    const int* dst = edge_index + E;

    char* ws = (char*)d_ws;
    size_t off = 0;
    auto alloc = [&](size_t bytes) -> void* {
        off = (off + 255) & ~(size_t)255;
        void* r = ws + off;
        off += bytes;
        return r;
    };
    int*    pc      = (int*)   alloc((size_t)NRANGE * NSLICE * RANGE * 4);   // 6.4 MB
    float*  pw      = (float*) alloc((size_t)NRANGE * NSLICE * RANGE * 4);   // 6.4 MB
    float*  dinv    = (float*) alloc((size_t)N * 4);
    int*    cnt     = (int*)   alloc((size_t)N * 4);
    int*    offs    = (int*)   alloc((size_t)(N + 1) * 4);
    int*    bsum    = (int*)   alloc(256 * 4);
    int*    es      = (int*)   alloc((size_t)E * 4);
    float*  en      = (float*) alloc((size_t)E * 4);
    ushort* h0_bf   = (ushort*)alloc((size_t)N * H * 2);
    ushort* agg1_bf = (ushort*)alloc((size_t)N * H * 2);
    ushort* W1T     = (ushort*)alloc((size_t)H * F * 2);
    ushort* WcT     = (ushort*)alloc((size_t)H2 * H * 2);
    float*  wmp     = (float*) alloc(H2 * 4);
    float*  wmq     = (float*) alloc(H2 * 4);
    float*  bpq     = (float*) alloc(2 * 4);
    float*  pe      = (float*) alloc((size_t)N * 4);
    float*  qe      = (float*) alloc((size_t)N * 4);
    float*  p       = (float*) alloc((size_t)N * 4);
    float*  q       = (float*) alloc((size_t)N * 4);
    (void)ws_size; (void)n_in; (void)out_size;

    int nbN  = (N + 255) / 256;
    int nbE  = (E + 255) / 256;
    int nblk = (N + 1023) / 1024;
    int nbW  = (int)(((size_t)N * 64 + 255) / 256);
    int nbM  = (N + 127) / 128;
    dim3 gridRB(NSLICE, NRANGE);

    // CSR build (no global atomics)
    part_hist<<<gridRB, 256, 0, stream>>>(dst, w, pc, pw, E, N, RANGE);
    reduce_part<<<nbN, 256, 0, stream>>>(pc, pw, cnt, dinv, N, RANGE);
    scan_partial<<<nblk, 1024, 0, stream>>>(cnt, offs, bsum, N);
    scan_bsum<<<1, 1, 0, stream>>>(bsum, offs, nblk, N);
    scan_add<<<nbN, 256, 0, stream>>>(offs, bsum, N);
    csr_scatter<<<gridRB, 256, 0, stream>>>(src, dst, w, dinv, offs, pc, es, en, E, N, RANGE);

    // weight prep
    tconv_kernel<<<(F * H + 255) / 256, 256, 0, stream>>>(W1, W1T, F, H);
    tconv_kernel<<<(H * H2 + 255) / 256, 256, 0, stream>>>(Wc, WcT, H, H2);
    fold_kernel<<<1, 256, 0, stream>>>(Wm, Wl, bm, wmp, wmq, bpq);

    // h0 = bf16(x @ W1 + b1)
    gemm1_mfma<<<nbM, 256, 0, stream>>>(x, W1T, b1, h0_bf, N);
    // agg1 = bf16(A @ h0)
    aggregate_bf16<<<nbW, 256, 0, stream>>>(h0_bf, offs, es, en, dinv, agg1_bf, N);
    // pe,qe = relu(agg1 @ Wc + bc) @ [wmp, wmq]
    gemm2_pq<<<nbM, 512, 0, stream>>>(agg1_bf, WcT, bc, wmp, wmq, pe, qe, N);
    // p,q scalar aggregation
    agg_scalar<<<nbN, 256, 0, stream>>>(pe, qe, offs, es, en, dinv, bpq, p, q, N);
    // out
    edge_out_kernel<<<nbE, 256, 0, stream>>>(src, dst, p, q, bl, out, E);
}

// Round 5
// 236.572 us; speedup vs baseline: 2.3075x; 1.1590x over previous
//
#include <hip/hip_runtime.h>
#include <hip/hip_bf16.h>
#include <math.h>

// GCN link predictor, bf16 MFMA pipeline, counting-sort CSR build with
// block-exclusive write regions (no global atomics, no partial-line writes).
//   bucket_count/scan/scatter: sort edges into 196 coarse buckets (dst>>8)
//   range_deg: per-range deg/dinv + offs (LDS scan + bucket base, no global scan)
//   csr_build: per-range CSR scatter into exclusive region
//   h0_bf = bf16(x @ W1 + b1)            [N,128]  MFMA GEMM
//   agg1_bf = bf16(A_norm @ h0_bf)       [N,128]  wave-per-node, 8-wide MLP
//   pe,qe = relu(agg1 @ Wc + bc) @ [wmp,wmq]      MFMA GEMM fused epilogue
//   p = A_norm @ pe ; q = A_norm @ qe              scalar aggregate, 4-wide MLP
//   out[e] = sigmoid(p[src] + q[dst] + bl)

#define NSL 256      // edge slices for bucketing passes
#define RSH 8        // log2(RANGE)
#define RNG 256      // nodes per range (LDS histogram width)

typedef __attribute__((ext_vector_type(8))) short bf16x8;
typedef __attribute__((ext_vector_type(4))) float f32x4;

static __device__ __forceinline__ ushort f2b(float f) {
    __hip_bfloat16 h = __float2bfloat16(f);
    return *(ushort*)&h;
}
static __device__ __forceinline__ float b2f(ushort u) {
    unsigned int v = ((unsigned int)u) << 16;
    return *(float*)&v;
}

// ---------------- CSR build: counting sort by range ----------------

// count edges per (slice, range)
__global__ __launch_bounds__(256) void bucket_count(const int* __restrict__ dst,
                                                    int* __restrict__ cntA, int E, int NR) {
    __shared__ int lc[256];
    const int b = blockIdx.x, t = threadIdx.x;
    lc[t] = 0;
    __syncthreads();
    const int beg = (int)((long long)b * E / NSL);
    const int end = (int)((long long)(b + 1) * E / NSL);
    for (int e = beg + t; e < end; e += 256) atomicAdd(&lc[dst[e] >> RSH], 1);
    __syncthreads();
    if (t < NR) cntA[b * NR + t] = lc[t];
}

// in-place exclusive prefix over slices + global bucket bases (single block)
__global__ __launch_bounds__(256) void bucket_scan(int* __restrict__ cntA,
                                                   int* __restrict__ baseOut, int NR, int E) {
    __shared__ int s_[256];
    const int r = threadIdx.x;
    int run = 0;
    if (r < NR) {
        for (int s = 0; s < NSL; ++s) {
            int c = cntA[s * NR + r];
            cntA[s * NR + r] = run;
            run += c;
        }
    }
    int v = run;
    s_[r] = v;
    __syncthreads();
    for (int off = 1; off < 256; off <<= 1) {
        int add = (r >= off) ? s_[r - off] : 0;
        __syncthreads();
        s_[r] += add;
        __syncthreads();
    }
    int base = s_[r] - v;   // exclusive over ranges
    if (r < NR) {
        baseOut[r] = base;
        for (int s = 0; s < NSL; ++s) cntA[s * NR + r] += base;
    }
    if (r == 0) baseOut[NR] = E;
}

// scatter edges to buckets: packB = (dstLocal<<24)|src, wB = w
__global__ __launch_bounds__(256) void bucket_scatter(const int* __restrict__ src,
                                                      const int* __restrict__ dst,
                                                      const float* __restrict__ w,
                                                      const int* __restrict__ cntA,
                                                      unsigned int* __restrict__ packB,
                                                      float* __restrict__ wB, int E, int NR) {
    __shared__ int cur[256];
    const int b = blockIdx.x, t = threadIdx.x;
    if (t < NR) cur[t] = cntA[b * NR + t];
    __syncthreads();
    const int beg = (int)((long long)b * E / NSL);
    const int end = (int)((long long)(b + 1) * E / NSL);
    for (int e = beg + t; e < end; e += 256) {
        int d = dst[e];
        int r = d >> RSH;
        int pos = atomicAdd(&cur[r], 1);
        packB[pos] = ((unsigned int)(d & (RNG - 1)) << 24) | (unsigned int)src[e];
        wB[pos] = w[e];
    }
}

// per-range: weighted degree -> dinv; per-node count -> offs (LDS scan + base)
__global__ __launch_bounds__(256) void range_deg(const unsigned int* __restrict__ packB,
                                                 const float* __restrict__ wB,
                                                 const int* __restrict__ baseOut,
                                                 float* __restrict__ dinv,
                                                 int* __restrict__ offs,
                                                 int N, int E) {
    __shared__ float lw[256];
    __shared__ int lc[256];
    __shared__ int sc[256];
    const int r = blockIdx.x, t = threadIdx.x;
    lw[t] = 0.f; lc[t] = 0;
    __syncthreads();
    const int beg = baseOut[r], end = baseOut[r + 1];
    for (int e = beg + t; e < end; e += 256) {
        unsigned int pk = packB[e];
        int dl = pk >> 24;
        atomicAdd(&lc[dl], 1);
        atomicAdd(&lw[dl], wB[e]);
    }
    __syncthreads();
    int v = lc[t];
    sc[t] = v;
    __syncthreads();
    for (int off = 1; off < 256; off <<= 1) {
        int add = (t >= off) ? sc[t - off] : 0;
        __syncthreads();
        sc[t] += add;
        __syncthreads();
    }
    int node = (r << RSH) + t;
    if (node < N) {
        dinv[node] = 1.0f / sqrtf(1.0f + lw[t]);   // self-loop weight 1
        offs[node] = beg + sc[t] - v;              // global CSR offset
    }
    if (r == 0 && t == 0) offs[N] = E;
}

// per-range CSR scatter (block-exclusive output region)
__global__ __launch_bounds__(256) void csr_build(const unsigned int* __restrict__ packB,
                                                 const float* __restrict__ wB,
                                                 const int* __restrict__ baseOut,
                                                 const float* __restrict__ dinv,
                                                 const int* __restrict__ offs,
                                                 int* __restrict__ es,
                                                 float* __restrict__ en, int N) {
    __shared__ int cur[256];
    __shared__ float ldv[256];
    const int r = blockIdx.x, t = threadIdx.x;
    const int node = (r << RSH) + t;
    cur[t] = (node < N) ? offs[node] : 0;
    ldv[t] = (node < N) ? dinv[node] : 0.f;
    __syncthreads();
    const int beg = baseOut[r], end = baseOut[r + 1];
    for (int e = beg + t; e < end; e += 256) {
        unsigned int pk = packB[e];
        int dl = pk >> 24;
        int s = pk & 0xFFFFFF;
        float nrm = dinv[s] * wB[e] * ldv[dl];
        int pos = atomicAdd(&cur[dl], 1);
        es[pos] = s;
        en[pos] = nrm;
    }
}

// ---------------- weight prep ----------------

__global__ __launch_bounds__(256) void tconv_kernel(const float* __restrict__ B,
                                                    ushort* __restrict__ BT, int K, int Nn) {
    int i = blockIdx.x * 256 + threadIdx.x;
    if (i < K * Nn) {
        int k = i / Nn, n = i % Nn;
        BT[(size_t)n * K + k] = f2b(B[i]);
    }
}

__global__ __launch_bounds__(256) void fold_kernel(const float* __restrict__ Wm,
                                                   const float* __restrict__ Wl,
                                                   const float* __restrict__ bm,
                                                   float* __restrict__ wmp,
                                                   float* __restrict__ wmq,
                                                   float* __restrict__ bpq) {
    int j = threadIdx.x;
    float sp = 0.f, sq = 0.f;
    for (int k = 0; k < 128; ++k) {
        float v = Wm[(size_t)j * 128 + k];
        sp += v * Wl[k];
        sq += v * Wl[128 + k];
    }
    wmp[j] = sp; wmq[j] = sq;
    if (j == 0) { float s = 0.f; for (int k = 0; k < 128; ++k) s += bm[k] * Wl[k];       bpq[0] = s; }
    if (j == 1) { float s = 0.f; for (int k = 0; k < 128; ++k) s += bm[k] * Wl[128 + k]; bpq[1] = s; }
}

// ---------------- GEMM1: h0_bf = bf16(x @ W1 + b1) ----------------
__global__ __launch_bounds__(256) void gemm1_mfma(const float* __restrict__ A,
                                                  const ushort* __restrict__ BT,
                                                  const float* __restrict__ bias,
                                                  ushort* __restrict__ C, int M) {
    __shared__ ushort As[128 * 64];
    __shared__ ushort Bs[128 * 64];
    const int t = threadIdx.x;
    const int bm = blockIdx.x * 128;
    const int lane = t & 63;
    const int wid = t >> 6;
    const int wm = (wid >> 1) * 64, wn = (wid & 1) * 64;

    f32x4 acc[4][4] = {};

    const int arow0 = wid * 32 + (lane >> 4);
    const int acol  = (lane & 15) * 4;
    const int brow0 = wid * 32 + (lane >> 3);
    const int bcol  = (lane & 7) * 8;

    float4 aReg[8];
    uint4  bReg[4];

    auto issue = [&](int k0) {
#pragma unroll
        for (int j = 0; j < 8; ++j) {
            int row = arow0 + j * 4;
            bool valid = (bm + row) < M;
            aReg[j] = valid ? *(const float4*)(A + (size_t)(bm + row) * 512 + k0 + acol)
                            : make_float4(0.f, 0.f, 0.f, 0.f);
        }
#pragma unroll
        for (int j = 0; j < 4; ++j) {
            int row = brow0 + j * 8;
            bReg[j] = *(const uint4*)(BT + (size_t)row * 512 + k0 + bcol);
        }
    };

    issue(0);

#pragma unroll 1
    for (int tt = 0; tt < 8; ++tt) {
#pragma unroll
        for (int j = 0; j < 8; ++j) {
            int row = arow0 + j * 4;
            ushort4 u;
            u.x = f2b(aReg[j].x); u.y = f2b(aReg[j].y); u.z = f2b(aReg[j].z); u.w = f2b(aReg[j].w);
            int byte = (row * 128 + acol * 2) ^ ((row & 7) << 4);
            *(ushort4*)((char*)As + byte) = u;
        }
#pragma unroll
        for (int j = 0; j < 4; ++j) {
            int row = brow0 + j * 8;
            int byte = (row * 128 + bcol * 2) ^ ((row & 7) << 4);
            *(uint4*)((char*)Bs + byte) = bReg[j];
        }
        if (tt < 7) issue((tt + 1) * 64);
        __syncthreads();
#pragma unroll
        for (int ks = 0; ks < 2; ++ks) {
            bf16x8 af[4], bfr[4];
#pragma unroll
            for (int mi = 0; mi < 4; ++mi) {
                int row = wm + mi * 16 + (lane & 15);
                int byte = (row * 128 + ks * 64 + (lane >> 4) * 16) ^ ((row & 7) << 4);
                af[mi] = *(bf16x8*)((char*)As + byte);
            }
#pragma unroll
            for (int ni = 0; ni < 4; ++ni) {
                int row = wn + ni * 16 + (lane & 15);
                int byte = (row * 128 + ks * 64 + (lane >> 4) * 16) ^ ((row & 7) << 4);
                bfr[ni] = *(bf16x8*)((char*)Bs + byte);
            }
#pragma unroll
            for (int mi = 0; mi < 4; ++mi)
#pragma unroll
                for (int ni = 0; ni < 4; ++ni)
                    acc[mi][ni] = __builtin_amdgcn_mfma_f32_16x16x32_bf16(af[mi], bfr[ni], acc[mi][ni], 0, 0, 0);
        }
        __syncthreads();
    }
#pragma unroll
    for (int ni = 0; ni < 4; ++ni) {
        int col = wn + ni * 16 + (lane & 15);
        float bv = bias[col];
#pragma unroll
        for (int mi = 0; mi < 4; ++mi)
#pragma unroll
            for (int r = 0; r < 4; ++r) {
                int row = bm + wm + mi * 16 + (lane >> 4) * 4 + r;
                if (row < M) C[(size_t)row * 128 + col] = f2b(acc[mi][ni][r] + bv);
            }
    }
}

// ---------------- aggregate (bf16 in/out), 8-wide MLP ----------------
__global__ __launch_bounds__(256) void aggregate_bf16(const ushort* __restrict__ h,
                                                      const int* __restrict__ offs,
                                                      const int* __restrict__ es,
                                                      const float* __restrict__ en,
                                                      const float* __restrict__ dinv,
                                                      ushort* __restrict__ out, int n) {
    int wave = (int)((blockIdx.x * (size_t)blockDim.x + threadIdx.x) >> 6);
    int lane = threadIdx.x & 63;
    if (wave >= n) return;
    float di = dinv[wave];
    float sw = di * di;
    unsigned int hv = *(const unsigned int*)(h + (size_t)wave * 128 + lane * 2);
    float ax = sw * b2f((ushort)(hv & 0xffff));
    float ay = sw * b2f((ushort)(hv >> 16));
    int beg = offs[wave], end = offs[wave + 1];
    for (int e = beg; e < end; e += 8) {
        int sx[8]; float wx[8];
#pragma unroll
        for (int j = 0; j < 8; ++j) {
            bool v = (e + j) < end;
            sx[j] = v ? es[e + j] : wave;
            wx[j] = v ? en[e + j] : 0.f;
        }
        unsigned int vv[8];
#pragma unroll
        for (int j = 0; j < 8; ++j)
            vv[j] = *(const unsigned int*)(h + (size_t)sx[j] * 128 + lane * 2);
#pragma unroll
        for (int j = 0; j < 8; ++j) {
            ax += wx[j] * b2f((ushort)(vv[j] & 0xffff));
            ay += wx[j] * b2f((ushort)(vv[j] >> 16));
        }
    }
    unsigned int o = (unsigned int)f2b(ax) | ((unsigned int)f2b(ay) << 16);
    *(unsigned int*)(out + (size_t)wave * 128 + lane * 2) = o;
}

// ---------------- GEMM2 fused: pe,qe = relu(agg1@Wc + bc) @ [wmp,wmq] ----------------
__global__ __launch_bounds__(512) void gemm2_pq(const ushort* __restrict__ A,
                                                const ushort* __restrict__ BT,
                                                const float* __restrict__ bc,
                                                const float* __restrict__ wmp,
                                                const float* __restrict__ wmq,
                                                float* __restrict__ pe,
                                                float* __restrict__ qe, int M) {
    __shared__ ushort As[128 * 64];
    __shared__ ushort Bs[256 * 64];
    __shared__ float partp[4][128];
    __shared__ float partq[4][128];
    const int t = threadIdx.x;
    const int bm = blockIdx.x * 128;
    const int lane = t & 63;
    const int wid = t >> 6;
    const int wm = (wid >> 2) * 64, wn = (wid & 3) * 64;

    f32x4 acc[4][4] = {};

    const int arow0 = wid * 16 + (lane >> 3);
    const int brow0 = wid * 32 + (lane >> 3);
    const int ccol  = (lane & 7) * 8;

    uint4 aReg[2];
    uint4 bReg[4];

    auto issue = [&](int k0) {
#pragma unroll
        for (int j = 0; j < 2; ++j) {
            int row = arow0 + j * 8;
            bool valid = (bm + row) < M;
            aReg[j] = valid ? *(const uint4*)(A + (size_t)(bm + row) * 128 + k0 + ccol)
                            : make_uint4(0, 0, 0, 0);
        }
#pragma unroll
        for (int j = 0; j < 4; ++j) {
            int row = brow0 + j * 8;
            bReg[j] = *(const uint4*)(BT + (size_t)row * 128 + k0 + ccol);
        }
    };

    issue(0);

#pragma unroll 1
    for (int tt = 0; tt < 2; ++tt) {
#pragma unroll
        for (int j = 0; j < 2; ++j) {
            int row = arow0 + j * 8;
            int byte = (row * 128 + ccol * 2) ^ ((row & 7) << 4);
            *(uint4*)((char*)As + byte) = aReg[j];
        }
#pragma unroll
        for (int j = 0; j < 4; ++j) {
            int row = brow0 + j * 8;
            int byte = (row * 128 + ccol * 2) ^ ((row & 7) << 4);
            *(uint4*)((char*)Bs + byte) = bReg[j];
        }
        if (tt < 1) issue(64);
        __syncthreads();
#pragma unroll
        for (int ks = 0; ks < 2; ++ks) {
            bf16x8 af[4], bfr[4];
#pragma unroll
            for (int mi = 0; mi < 4; ++mi) {
                int row = wm + mi * 16 + (lane & 15);
                int byte = (row * 128 + ks * 64 + (lane >> 4) * 16) ^ ((row & 7) << 4);
                af[mi] = *(bf16x8*)((char*)As + byte);
            }
#pragma unroll
            for (int ni = 0; ni < 4; ++ni) {
                int row = wn + ni * 16 + (lane & 15);
                int byte = (row * 128 + ks * 64 + (lane >> 4) * 16) ^ ((row & 7) << 4);
                bfr[ni] = *(bf16x8*)((char*)Bs + byte);
            }
#pragma unroll
            for (int mi = 0; mi < 4; ++mi)
#pragma unroll
                for (int ni = 0; ni < 4; ++ni)
                    acc[mi][ni] = __builtin_amdgcn_mfma_f32_16x16x32_bf16(af[mi], bfr[ni], acc[mi][ni], 0, 0, 0);
        }
        __syncthreads();
    }

    float bcv[4], wpv[4], wqv[4];
#pragma unroll
    for (int ni = 0; ni < 4; ++ni) {
        int col = wn + ni * 16 + (lane & 15);
        bcv[ni] = bc[col];
        wpv[ni] = wmp[col];
        wqv[ni] = wmq[col];
    }
#pragma unroll
    for (int mi = 0; mi < 4; ++mi) {
#pragma unroll
        for (int r = 0; r < 4; ++r) {
            float sp = 0.f, sq = 0.f;
#pragma unroll
            for (int ni = 0; ni < 4; ++ni) {
                float h = fmaxf(acc[mi][ni][r] + bcv[ni], 0.f);
                sp += h * wpv[ni];
                sq += h * wqv[ni];
            }
#pragma unroll
            for (int off = 1; off < 16; off <<= 1) {
                sp += __shfl_xor(sp, off);
                sq += __shfl_xor(sq, off);
            }
            if ((lane & 15) == 0) {
                int row = wm + mi * 16 + (lane >> 4) * 4 + r;
                partp[wid & 3][row] = sp;
                partq[wid & 3][row] = sq;
            }
        }
    }
    __syncthreads();
    if (t < 128) {
        int row = t;
        if (bm + row < M)
            pe[bm + row] = partp[0][row] + partp[1][row] + partp[2][row] + partp[3][row];
    } else if (t < 256) {
        int row = t - 128;
        if (bm + row < M)
            qe[bm + row] = partq[0][row] + partq[1][row] + partq[2][row] + partq[3][row];
    }
}

// ---------------- scalar aggregation: p = A@pe + bp, q = A@qe + bq (4-wide MLP) ----------------
__global__ __launch_bounds__(256) void agg_scalar(const float* __restrict__ pe,
                                                  const float* __restrict__ qe,
                                                  const int* __restrict__ offs,
                                                  const int* __restrict__ es,
                                                  const float* __restrict__ en,
                                                  const float* __restrict__ dinv,
                                                  const float* __restrict__ bpq,
                                                  float* __restrict__ p,
                                                  float* __restrict__ q, int n) {
    int i = blockIdx.x * 256 + threadIdx.x;
    if (i >= n) return;
    float di = dinv[i];
    float sw = di * di;
    float ap = sw * pe[i], aq = sw * qe[i];
    int beg = offs[i], end = offs[i + 1];
    for (int k = beg; k < end; k += 4) {
        int sx[4]; float wx[4];
#pragma unroll
        for (int j = 0; j < 4; ++j) {
            bool v = (k + j) < end;
            sx[j] = v ? es[k + j] : i;
            wx[j] = v ? en[k + j] : 0.f;
        }
        float pv[4], qv[4];
#pragma unroll
        for (int j = 0; j < 4; ++j) { pv[j] = pe[sx[j]]; qv[j] = qe[sx[j]]; }
#pragma unroll
        for (int j = 0; j < 4; ++j) { ap += wx[j] * pv[j]; aq += wx[j] * qv[j]; }
    }
    p[i] = ap + bpq[0];
    q[i] = aq + bpq[1];
}

__global__ __launch_bounds__(256) void edge_out_kernel(const int* __restrict__ src,
                                                       const int* __restrict__ dst,
                                                       const float* __restrict__ p,
                                                       const float* __restrict__ q,
                                                       const float* __restrict__ bl,
                                                       float* __restrict__ out, int e) {
    int i = blockIdx.x * 256 + threadIdx.x;
    if (i < e) {
        float t = p[src[i]] + q[dst[i]] + bl[0];
        out[i] = 1.0f / (1.0f + expf(-t));
    }
}

// ---------------- launch ----------------

extern "C" void kernel_launch(void* const* d_in, const int* in_sizes, int n_in,
                              void* d_out, int out_size, void* d_ws, size_t ws_size,
                              hipStream_t stream) {
    const int*   edge_index = (const int*)d_in[0];
    const float* x   = (const float*)d_in[1];
    const float* w   = (const float*)d_in[2];
    const float* W1  = (const float*)d_in[3];
    const float* b1  = (const float*)d_in[4];
    const float* Wc  = (const float*)d_in[5];
    const float* bc  = (const float*)d_in[6];
    const float* Wm  = (const float*)d_in[7];
    const float* bm  = (const float*)d_in[8];
    const float* Wl  = (const float*)d_in[9];
    const float* bl  = (const float*)d_in[10];
    float* out = (float*)d_out;

    const int E  = in_sizes[2];            // 800000
    const int H  = in_sizes[4];            // 128
    const int F  = in_sizes[3] / H;        // 512
    const int N  = in_sizes[1] / F;        // 50000
    const int H2 = 2 * H;                  // 256
    const int NR = (N + RNG - 1) / RNG;    // 196 ranges (<= 256)

    const int* src = edge_index;
    const int* dst = edge_index + E;

    char* ws = (char*)d_ws;
    size_t off = 0;
    auto alloc = [&](size_t bytes) -> void* {
        off = (off + 255) & ~(size_t)255;
        void* r = ws + off;
        off += bytes;
        return r;
    };
    int*          cntA    = (int*)         alloc((size_t)NSL * NR * 4);
    int*          baseOut = (int*)         alloc((size_t)(NR + 1) * 4);
    unsigned int* packB   = (unsigned int*)alloc((size_t)E * 4);
    float*        wB      = (float*)       alloc((size_t)E * 4);
    float*        dinv    = (float*)       alloc((size_t)N * 4);
    int*          offs    = (int*)         alloc((size_t)(N + 1) * 4);
    int*          es      = (int*)         alloc((size_t)E * 4);
    float*        en      = (float*)       alloc((size_t)E * 4);
    ushort*       h0_bf   = (ushort*)      alloc((size_t)N * H * 2);
    ushort*       agg1_bf = (ushort*)      alloc((size_t)N * H * 2);
    ushort*       W1T     = (ushort*)      alloc((size_t)H * F * 2);
    ushort*       WcT     = (ushort*)      alloc((size_t)H2 * H * 2);
    float*        wmp     = (float*)       alloc(H2 * 4);
    float*        wmq     = (float*)       alloc(H2 * 4);
    float*        bpq     = (float*)       alloc(2 * 4);
    float*        pe      = (float*)       alloc((size_t)N * 4);
    float*        qe      = (float*)       alloc((size_t)N * 4);
    float*        p       = (float*)       alloc((size_t)N * 4);
    float*        q       = (float*)       alloc((size_t)N * 4);
    (void)ws_size; (void)n_in; (void)out_size;

    int nbN = (N + 255) / 256;
    int nbE = (E + 255) / 256;
    int nbW = (int)(((size_t)N * 64 + 255) / 256);
    int nbM = (N + 127) / 128;

    // CSR build: counting sort by range, block-exclusive writes
    bucket_count<<<NSL, 256, 0, stream>>>(dst, cntA, E, NR);
    bucket_scan<<<1, 256, 0, stream>>>(cntA, baseOut, NR, E);
    bucket_scatter<<<NSL, 256, 0, stream>>>(src, dst, w, cntA, packB, wB, E, NR);
    range_deg<<<NR, 256, 0, stream>>>(packB, wB, baseOut, dinv, offs, N, E);
    csr_build<<<NR, 256, 0, stream>>>(packB, wB, baseOut, dinv, offs, es, en, N);

    // weight prep
    tconv_kernel<<<(F * H + 255) / 256, 256, 0, stream>>>(W1, W1T, F, H);
    tconv_kernel<<<(H * H2 + 255) / 256, 256, 0, stream>>>(Wc, WcT, H, H2);
    fold_kernel<<<1, 256, 0, stream>>>(Wm, Wl, bm, wmp, wmq, bpq);

    // h0 = bf16(x @ W1 + b1)
    gemm1_mfma<<<nbM, 256, 0, stream>>>(x, W1T, b1, h0_bf, N);
    // agg1 = bf16(A @ h0)
    aggregate_bf16<<<nbW, 256, 0, stream>>>(h0_bf, offs, es, en, dinv, agg1_bf, N);
    // pe,qe = relu(agg1 @ Wc + bc) @ [wmp, wmq]
    gemm2_pq<<<nbM, 512, 0, stream>>>(agg1_bf, WcT, bc, wmp, wmq, pe, qe, N);
    // p,q scalar aggregation
    agg_scalar<<<nbN, 256, 0, stream>>>(pe, qe, offs, es, en, dinv, bpq, p, q, N);
    // out
    edge_out_kernel<<<nbE, 256, 0, stream>>>(src, dst, p, q, bl, out, E);
}

// Round 6
// 178.878 us; speedup vs baseline: 3.0517x; 1.3225x over previous
//
#include <hip/hip_runtime.h>
#include <hip/hip_bf16.h>
#include <math.h>

// GCN link predictor, bf16 MFMA pipeline, counting-sort CSR build with
// block-exclusive write regions and fully parallel scans.
//   bucket_count: per-slice LDS histogram over 196 ranges (dst>>8)
//   range_scan:   per-range parallel scan over slices -> slice cursors + range totals
//   base_scan:    1-block scan over 196 range totals -> bucket bases
//   bucket_scatter: sort edges into buckets (base folded in at cursor load)
//   range_deg:    per-range deg/dinv + offs (LDS scan + bucket base)
//   csr_build:    per-range CSR scatter into exclusive region
//   h0_bf = bf16(x @ W1 + b1)            [N,128]  MFMA GEMM
//   agg1_bf = bf16(A_norm @ h0_bf)       [N,128]  wave-per-node, 8-wide MLP
//   pe,qe = relu(agg1 @ Wc + bc) @ [wmp,wmq]      MFMA GEMM fused epilogue
//   p = A_norm @ pe ; q = A_norm @ qe              scalar aggregate, 4-wide MLP
//   out[e] = sigmoid(p[src] + q[dst] + bl)

#define NSL 256      // edge slices for bucketing passes
#define RSH 8        // log2(RANGE)
#define RNG 256      // nodes per range (LDS histogram width)

typedef __attribute__((ext_vector_type(8))) short bf16x8;
typedef __attribute__((ext_vector_type(4))) float f32x4;

static __device__ __forceinline__ ushort f2b(float f) {
    __hip_bfloat16 h = __float2bfloat16(f);
    return *(ushort*)&h;
}
static __device__ __forceinline__ float b2f(ushort u) {
    unsigned int v = ((unsigned int)u) << 16;
    return *(float*)&v;
}

// ---------------- CSR build: counting sort by range ----------------

// count edges per (slice, range); cntA layout [NSL][NR]
__global__ __launch_bounds__(256) void bucket_count(const int* __restrict__ dst,
                                                    int* __restrict__ cntA, int E, int NR) {
    __shared__ int lc[256];
    const int b = blockIdx.x, t = threadIdx.x;
    lc[t] = 0;
    __syncthreads();
    const int beg = (int)((long long)b * E / NSL);
    const int end = (int)((long long)(b + 1) * E / NSL);
    for (int e = beg + t; e < end; e += 256) atomicAdd(&lc[dst[e] >> RSH], 1);
    __syncthreads();
    if (t < NR) cntA[b * NR + t] = lc[t];
}

// per-range parallel scan over slices: block r, thread t = slice t.
// cntA[t][r] <- exclusive prefix; rtot[r] = total.
__global__ __launch_bounds__(256) void range_scan(int* __restrict__ cntA,
                                                  int* __restrict__ rtot, int NR) {
    __shared__ int s_[256];
    const int r = blockIdx.x, t = threadIdx.x;
    int v = cntA[t * NR + r];
    s_[t] = v;
    __syncthreads();
    for (int off = 1; off < 256; off <<= 1) {
        int add = (t >= off) ? s_[t - off] : 0;
        __syncthreads();
        s_[t] += add;
        __syncthreads();
    }
    cntA[t * NR + r] = s_[t] - v;        // exclusive within range, over slices
    if (t == 255) rtot[r] = s_[t];       // range total
}

// single-block scan over range totals -> bucket bases
__global__ __launch_bounds__(256) void base_scan(const int* __restrict__ rtot,
                                                 int* __restrict__ baseOut, int NR) {
    __shared__ int s_[256];
    const int t = threadIdx.x;
    int v = (t < NR) ? rtot[t] : 0;
    s_[t] = v;
    __syncthreads();
    for (int off = 1; off < 256; off <<= 1) {
        int add = (t >= off) ? s_[t - off] : 0;
        __syncthreads();
        s_[t] += add;
        __syncthreads();
    }
    if (t < NR) baseOut[t] = s_[t] - v;
    if (t == NR - 1) baseOut[NR] = s_[t];   // == E
}

// scatter edges to buckets: packB = (dstLocal<<24)|src, wB = w
__global__ __launch_bounds__(256) void bucket_scatter(const int* __restrict__ src,
                                                      const int* __restrict__ dst,
                                                      const float* __restrict__ w,
                                                      const int* __restrict__ cntA,
                                                      const int* __restrict__ baseOut,
                                                      unsigned int* __restrict__ packB,
                                                      float* __restrict__ wB, int E, int NR) {
    __shared__ int cur[256];
    const int b = blockIdx.x, t = threadIdx.x;
    if (t < NR) cur[t] = cntA[b * NR + t] + baseOut[t];
    __syncthreads();
    const int beg = (int)((long long)b * E / NSL);
    const int end = (int)((long long)(b + 1) * E / NSL);
    for (int e = beg + t; e < end; e += 256) {
        int d = dst[e];
        int r = d >> RSH;
        int pos = atomicAdd(&cur[r], 1);
        packB[pos] = ((unsigned int)(d & (RNG - 1)) << 24) | (unsigned int)src[e];
        wB[pos] = w[e];
    }
}

// per-range: weighted degree -> dinv; per-node count -> offs (LDS scan + base)
__global__ __launch_bounds__(256) void range_deg(const unsigned int* __restrict__ packB,
                                                 const float* __restrict__ wB,
                                                 const int* __restrict__ baseOut,
                                                 float* __restrict__ dinv,
                                                 int* __restrict__ offs,
                                                 int N, int E) {
    __shared__ float lw[256];
    __shared__ int lc[256];
    __shared__ int sc[256];
    const int r = blockIdx.x, t = threadIdx.x;
    lw[t] = 0.f; lc[t] = 0;
    __syncthreads();
    const int beg = baseOut[r], end = baseOut[r + 1];
    for (int e = beg + t; e < end; e += 256) {
        unsigned int pk = packB[e];
        int dl = pk >> 24;
        atomicAdd(&lc[dl], 1);
        atomicAdd(&lw[dl], wB[e]);
    }
    __syncthreads();
    int v = lc[t];
    sc[t] = v;
    __syncthreads();
    for (int off = 1; off < 256; off <<= 1) {
        int add = (t >= off) ? sc[t - off] : 0;
        __syncthreads();
        sc[t] += add;
        __syncthreads();
    }
    int node = (r << RSH) + t;
    if (node < N) {
        dinv[node] = 1.0f / sqrtf(1.0f + lw[t]);   // self-loop weight 1
        offs[node] = beg + sc[t] - v;              // global CSR offset
    }
    if (r == 0 && t == 0) offs[N] = E;
}

// per-range CSR scatter (block-exclusive output region)
__global__ __launch_bounds__(256) void csr_build(const unsigned int* __restrict__ packB,
                                                 const float* __restrict__ wB,
                                                 const int* __restrict__ baseOut,
                                                 const float* __restrict__ dinv,
                                                 const int* __restrict__ offs,
                                                 int* __restrict__ es,
                                                 float* __restrict__ en, int N) {
    __shared__ int cur[256];
    __shared__ float ldv[256];
    const int r = blockIdx.x, t = threadIdx.x;
    const int node = (r << RSH) + t;
    cur[t] = (node < N) ? offs[node] : 0;
    ldv[t] = (node < N) ? dinv[node] : 0.f;
    __syncthreads();
    const int beg = baseOut[r], end = baseOut[r + 1];
    for (int e = beg + t; e < end; e += 256) {
        unsigned int pk = packB[e];
        int dl = pk >> 24;
        int s = pk & 0xFFFFFF;
        float nrm = dinv[s] * wB[e] * ldv[dl];
        int pos = atomicAdd(&cur[dl], 1);
        es[pos] = s;
        en[pos] = nrm;
    }
}

// ---------------- weight prep ----------------

__global__ __launch_bounds__(256) void tconv_kernel(const float* __restrict__ B,
                                                    ushort* __restrict__ BT, int K, int Nn) {
    int i = blockIdx.x * 256 + threadIdx.x;
    if (i < K * Nn) {
        int k = i / Nn, n = i % Nn;
        BT[(size_t)n * K + k] = f2b(B[i]);
    }
}

__global__ __launch_bounds__(256) void fold_kernel(const float* __restrict__ Wm,
                                                   const float* __restrict__ Wl,
                                                   const float* __restrict__ bm,
                                                   float* __restrict__ wmp,
                                                   float* __restrict__ wmq,
                                                   float* __restrict__ bpq) {
    int j = threadIdx.x;
    float sp = 0.f, sq = 0.f;
    for (int k = 0; k < 128; ++k) {
        float v = Wm[(size_t)j * 128 + k];
        sp += v * Wl[k];
        sq += v * Wl[128 + k];
    }
    wmp[j] = sp; wmq[j] = sq;
    if (j == 0) { float s = 0.f; for (int k = 0; k < 128; ++k) s += bm[k] * Wl[k];       bpq[0] = s; }
    if (j == 1) { float s = 0.f; for (int k = 0; k < 128; ++k) s += bm[k] * Wl[128 + k]; bpq[1] = s; }
}

// ---------------- GEMM1: h0_bf = bf16(x @ W1 + b1) ----------------
__global__ __launch_bounds__(256) void gemm1_mfma(const float* __restrict__ A,
                                                  const ushort* __restrict__ BT,
                                                  const float* __restrict__ bias,
                                                  ushort* __restrict__ C, int M) {
    __shared__ ushort As[128 * 64];
    __shared__ ushort Bs[128 * 64];
    const int t = threadIdx.x;
    const int bm = blockIdx.x * 128;
    const int lane = t & 63;
    const int wid = t >> 6;
    const int wm = (wid >> 1) * 64, wn = (wid & 1) * 64;

    f32x4 acc[4][4] = {};

    const int arow0 = wid * 32 + (lane >> 4);
    const int acol  = (lane & 15) * 4;
    const int brow0 = wid * 32 + (lane >> 3);
    const int bcol  = (lane & 7) * 8;

    float4 aReg[8];
    uint4  bReg[4];

    auto issue = [&](int k0) {
#pragma unroll
        for (int j = 0; j < 8; ++j) {
            int row = arow0 + j * 4;
            bool valid = (bm + row) < M;
            aReg[j] = valid ? *(const float4*)(A + (size_t)(bm + row) * 512 + k0 + acol)
                            : make_float4(0.f, 0.f, 0.f, 0.f);
        }
#pragma unroll
        for (int j = 0; j < 4; ++j) {
            int row = brow0 + j * 8;
            bReg[j] = *(const uint4*)(BT + (size_t)row * 512 + k0 + bcol);
        }
    };

    issue(0);

#pragma unroll 1
    for (int tt = 0; tt < 8; ++tt) {
#pragma unroll
        for (int j = 0; j < 8; ++j) {
            int row = arow0 + j * 4;
            ushort4 u;
            u.x = f2b(aReg[j].x); u.y = f2b(aReg[j].y); u.z = f2b(aReg[j].z); u.w = f2b(aReg[j].w);
            int byte = (row * 128 + acol * 2) ^ ((row & 7) << 4);
            *(ushort4*)((char*)As + byte) = u;
        }
#pragma unroll
        for (int j = 0; j < 4; ++j) {
            int row = brow0 + j * 8;
            int byte = (row * 128 + bcol * 2) ^ ((row & 7) << 4);
            *(uint4*)((char*)Bs + byte) = bReg[j];
        }
        if (tt < 7) issue((tt + 1) * 64);
        __syncthreads();
#pragma unroll
        for (int ks = 0; ks < 2; ++ks) {
            bf16x8 af[4], bfr[4];
#pragma unroll
            for (int mi = 0; mi < 4; ++mi) {
                int row = wm + mi * 16 + (lane & 15);
                int byte = (row * 128 + ks * 64 + (lane >> 4) * 16) ^ ((row & 7) << 4);
                af[mi] = *(bf16x8*)((char*)As + byte);
            }
#pragma unroll
            for (int ni = 0; ni < 4; ++ni) {
                int row = wn + ni * 16 + (lane & 15);
                int byte = (row * 128 + ks * 64 + (lane >> 4) * 16) ^ ((row & 7) << 4);
                bfr[ni] = *(bf16x8*)((char*)Bs + byte);
            }
#pragma unroll
            for (int mi = 0; mi < 4; ++mi)
#pragma unroll
                for (int ni = 0; ni < 4; ++ni)
                    acc[mi][ni] = __builtin_amdgcn_mfma_f32_16x16x32_bf16(af[mi], bfr[ni], acc[mi][ni], 0, 0, 0);
        }
        __syncthreads();
    }
#pragma unroll
    for (int ni = 0; ni < 4; ++ni) {
        int col = wn + ni * 16 + (lane & 15);
        float bv = bias[col];
#pragma unroll
        for (int mi = 0; mi < 4; ++mi)
#pragma unroll
            for (int r = 0; r < 4; ++r) {
                int row = bm + wm + mi * 16 + (lane >> 4) * 4 + r;
                if (row < M) C[(size_t)row * 128 + col] = f2b(acc[mi][ni][r] + bv);
            }
    }
}

// ---------------- aggregate (bf16 in/out), 8-wide MLP ----------------
__global__ __launch_bounds__(256) void aggregate_bf16(const ushort* __restrict__ h,
                                                      const int* __restrict__ offs,
                                                      const int* __restrict__ es,
                                                      const float* __restrict__ en,
                                                      const float* __restrict__ dinv,
                                                      ushort* __restrict__ out, int n) {
    int wave = (int)((blockIdx.x * (size_t)blockDim.x + threadIdx.x) >> 6);
    int lane = threadIdx.x & 63;
    if (wave >= n) return;
    float di = dinv[wave];
    float sw = di * di;
    unsigned int hv = *(const unsigned int*)(h + (size_t)wave * 128 + lane * 2);
    float ax = sw * b2f((ushort)(hv & 0xffff));
    float ay = sw * b2f((ushort)(hv >> 16));
    int beg = offs[wave], end = offs[wave + 1];
    for (int e = beg; e < end; e += 8) {
        int sx[8]; float wx[8];
#pragma unroll
        for (int j = 0; j < 8; ++j) {
            bool v = (e + j) < end;
            sx[j] = v ? es[e + j] : wave;
            wx[j] = v ? en[e + j] : 0.f;
        }
        unsigned int vv[8];
#pragma unroll
        for (int j = 0; j < 8; ++j)
            vv[j] = *(const unsigned int*)(h + (size_t)sx[j] * 128 + lane * 2);
#pragma unroll
        for (int j = 0; j < 8; ++j) {
            ax += wx[j] * b2f((ushort)(vv[j] & 0xffff));
            ay += wx[j] * b2f((ushort)(vv[j] >> 16));
        }
    }
    unsigned int o = (unsigned int)f2b(ax) | ((unsigned int)f2b(ay) << 16);
    *(unsigned int*)(out + (size_t)wave * 128 + lane * 2) = o;
}

// ---------------- GEMM2 fused: pe,qe = relu(agg1@Wc + bc) @ [wmp,wmq] ----------------
__global__ __launch_bounds__(512) void gemm2_pq(const ushort* __restrict__ A,
                                                const ushort* __restrict__ BT,
                                                const float* __restrict__ bc,
                                                const float* __restrict__ wmp,
                                                const float* __restrict__ wmq,
                                                float* __restrict__ pe,
                                                float* __restrict__ qe, int M) {
    __shared__ ushort As[128 * 64];
    __shared__ ushort Bs[256 * 64];
    __shared__ float partp[4][128];
    __shared__ float partq[4][128];
    const int t = threadIdx.x;
    const int bm = blockIdx.x * 128;
    const int lane = t & 63;
    const int wid = t >> 6;
    const int wm = (wid >> 2) * 64, wn = (wid & 3) * 64;

    f32x4 acc[4][4] = {};

    const int arow0 = wid * 16 + (lane >> 3);
    const int brow0 = wid * 32 + (lane >> 3);
    const int ccol  = (lane & 7) * 8;

    uint4 aReg[2];
    uint4 bReg[4];

    auto issue = [&](int k0) {
#pragma unroll
        for (int j = 0; j < 2; ++j) {
            int row = arow0 + j * 8;
            bool valid = (bm + row) < M;
            aReg[j] = valid ? *(const uint4*)(A + (size_t)(bm + row) * 128 + k0 + ccol)
                            : make_uint4(0, 0, 0, 0);
        }
#pragma unroll
        for (int j = 0; j < 4; ++j) {
            int row = brow0 + j * 8;
            bReg[j] = *(const uint4*)(BT + (size_t)row * 128 + k0 + ccol);
        }
    };

    issue(0);

#pragma unroll 1
    for (int tt = 0; tt < 2; ++tt) {
#pragma unroll
        for (int j = 0; j < 2; ++j) {
            int row = arow0 + j * 8;
            int byte = (row * 128 + ccol * 2) ^ ((row & 7) << 4);
            *(uint4*)((char*)As + byte) = aReg[j];
        }
#pragma unroll
        for (int j = 0; j < 4; ++j) {
            int row = brow0 + j * 8;
            int byte = (row * 128 + ccol * 2) ^ ((row & 7) << 4);
            *(uint4*)((char*)Bs + byte) = bReg[j];
        }
        if (tt < 1) issue(64);
        __syncthreads();
#pragma unroll
        for (int ks = 0; ks < 2; ++ks) {
            bf16x8 af[4], bfr[4];
#pragma unroll
            for (int mi = 0; mi < 4; ++mi) {
                int row = wm + mi * 16 + (lane & 15);
                int byte = (row * 128 + ks * 64 + (lane >> 4) * 16) ^ ((row & 7) << 4);
                af[mi] = *(bf16x8*)((char*)As + byte);
            }
#pragma unroll
            for (int ni = 0; ni < 4; ++ni) {
                int row = wn + ni * 16 + (lane & 15);
                int byte = (row * 128 + ks * 64 + (lane >> 4) * 16) ^ ((row & 7) << 4);
                bfr[ni] = *(bf16x8*)((char*)Bs + byte);
            }
#pragma unroll
            for (int mi = 0; mi < 4; ++mi)
#pragma unroll
                for (int ni = 0; ni < 4; ++ni)
                    acc[mi][ni] = __builtin_amdgcn_mfma_f32_16x16x32_bf16(af[mi], bfr[ni], acc[mi][ni], 0, 0, 0);
        }
        __syncthreads();
    }

    float bcv[4], wpv[4], wqv[4];
#pragma unroll
    for (int ni = 0; ni < 4; ++ni) {
        int col = wn + ni * 16 + (lane & 15);
        bcv[ni] = bc[col];
        wpv[ni] = wmp[col];
        wqv[ni] = wmq[col];
    }
#pragma unroll
    for (int mi = 0; mi < 4; ++mi) {
#pragma unroll
        for (int r = 0; r < 4; ++r) {
            float sp = 0.f, sq = 0.f;
#pragma unroll
            for (int ni = 0; ni < 4; ++ni) {
                float h = fmaxf(acc[mi][ni][r] + bcv[ni], 0.f);
                sp += h * wpv[ni];
                sq += h * wqv[ni];
            }
#pragma unroll
            for (int off = 1; off < 16; off <<= 1) {
                sp += __shfl_xor(sp, off);
                sq += __shfl_xor(sq, off);
            }
            if ((lane & 15) == 0) {
                int row = wm + mi * 16 + (lane >> 4) * 4 + r;
                partp[wid & 3][row] = sp;
                partq[wid & 3][row] = sq;
            }
        }
    }
    __syncthreads();
    if (t < 128) {
        int row = t;
        if (bm + row < M)
            pe[bm + row] = partp[0][row] + partp[1][row] + partp[2][row] + partp[3][row];
    } else if (t < 256) {
        int row = t - 128;
        if (bm + row < M)
            qe[bm + row] = partq[0][row] + partq[1][row] + partq[2][row] + partq[3][row];
    }
}

// ---------------- scalar aggregation: p = A@pe + bp, q = A@qe + bq (4-wide MLP) ----------------
__global__ __launch_bounds__(256) void agg_scalar(const float* __restrict__ pe,
                                                  const float* __restrict__ qe,
                                                  const int* __restrict__ offs,
                                                  const int* __restrict__ es,
                                                  const float* __restrict__ en,
                                                  const float* __restrict__ dinv,
                                                  const float* __restrict__ bpq,
                                                  float* __restrict__ p,
                                                  float* __restrict__ q, int n) {
    int i = blockIdx.x * 256 + threadIdx.x;
    if (i >= n) return;
    float di = dinv[i];
    float sw = di * di;
    float ap = sw * pe[i], aq = sw * qe[i];
    int beg = offs[i], end = offs[i + 1];
    for (int k = beg; k < end; k += 4) {
        int sx[4]; float wx[4];
#pragma unroll
        for (int j = 0; j < 4; ++j) {
            bool v = (k + j) < end;
            sx[j] = v ? es[k + j] : i;
            wx[j] = v ? en[k + j] : 0.f;
        }
        float pv[4], qv[4];
#pragma unroll
        for (int j = 0; j < 4; ++j) { pv[j] = pe[sx[j]]; qv[j] = qe[sx[j]]; }
#pragma unroll
        for (int j = 0; j < 4; ++j) { ap += wx[j] * pv[j]; aq += wx[j] * qv[j]; }
    }
    p[i] = ap + bpq[0];
    q[i] = aq + bpq[1];
}

__global__ __launch_bounds__(256) void edge_out_kernel(const int* __restrict__ src,
                                                       const int* __restrict__ dst,
                                                       const float* __restrict__ p,
                                                       const float* __restrict__ q,
                                                       const float* __restrict__ bl,
                                                       float* __restrict__ out, int e) {
    int i = blockIdx.x * 256 + threadIdx.x;
    if (i < e) {
        float t = p[src[i]] + q[dst[i]] + bl[0];
        out[i] = 1.0f / (1.0f + expf(-t));
    }
}

// ---------------- launch ----------------

extern "C" void kernel_launch(void* const* d_in, const int* in_sizes, int n_in,
                              void* d_out, int out_size, void* d_ws, size_t ws_size,
                              hipStream_t stream) {
    const int*   edge_index = (const int*)d_in[0];
    const float* x   = (const float*)d_in[1];
    const float* w   = (const float*)d_in[2];
    const float* W1  = (const float*)d_in[3];
    const float* b1  = (const float*)d_in[4];
    const float* Wc  = (const float*)d_in[5];
    const float* bc  = (const float*)d_in[6];
    const float* Wm  = (const float*)d_in[7];
    const float* bm  = (const float*)d_in[8];
    const float* Wl  = (const float*)d_in[9];
    const float* bl  = (const float*)d_in[10];
    float* out = (float*)d_out;

    const int E  = in_sizes[2];            // 800000
    const int H  = in_sizes[4];            // 128
    const int F  = in_sizes[3] / H;        // 512
    const int N  = in_sizes[1] / F;        // 50000
    const int H2 = 2 * H;                  // 256
    const int NR = (N + RNG - 1) / RNG;    // 196 ranges (<= 256)

    const int* src = edge_index;
    const int* dst = edge_index + E;

    char* ws = (char*)d_ws;
    size_t off = 0;
    auto alloc = [&](size_t bytes) -> void* {
        off = (off + 255) & ~(size_t)255;
        void* r = ws + off;
        off += bytes;
        return r;
    };
    int*          cntA    = (int*)         alloc((size_t)NSL * NR * 4);
    int*          rtot    = (int*)         alloc((size_t)NR * 4);
    int*          baseOut = (int*)         alloc((size_t)(NR + 1) * 4);
    unsigned int* packB   = (unsigned int*)alloc((size_t)E * 4);
    float*        wB      = (float*)       alloc((size_t)E * 4);
    float*        dinv    = (float*)       alloc((size_t)N * 4);
    int*          offs    = (int*)         alloc((size_t)(N + 1) * 4);
    int*          es      = (int*)         alloc((size_t)E * 4);
    float*        en      = (float*)       alloc((size_t)E * 4);
    ushort*       h0_bf   = (ushort*)      alloc((size_t)N * H * 2);
    ushort*       agg1_bf = (ushort*)      alloc((size_t)N * H * 2);
    ushort*       W1T     = (ushort*)      alloc((size_t)H * F * 2);
    ushort*       WcT     = (ushort*)      alloc((size_t)H2 * H * 2);
    float*        wmp     = (float*)       alloc(H2 * 4);
    float*        wmq     = (float*)       alloc(H2 * 4);
    float*        bpq     = (float*)       alloc(2 * 4);
    float*        pe      = (float*)       alloc((size_t)N * 4);
    float*        qe      = (float*)       alloc((size_t)N * 4);
    float*        p       = (float*)       alloc((size_t)N * 4);
    float*        q       = (float*)       alloc((size_t)N * 4);
    (void)ws_size; (void)n_in; (void)out_size;

    int nbN = (N + 255) / 256;
    int nbE = (E + 255) / 256;
    int nbW = (int)(((size_t)N * 64 + 255) / 256);
    int nbM = (N + 127) / 128;

    // CSR build: counting sort by range, block-exclusive writes, parallel scans
    bucket_count<<<NSL, 256, 0, stream>>>(dst, cntA, E, NR);
    range_scan<<<NR, 256, 0, stream>>>(cntA, rtot, NR);
    base_scan<<<1, 256, 0, stream>>>(rtot, baseOut, NR);
    bucket_scatter<<<NSL, 256, 0, stream>>>(src, dst, w, cntA, baseOut, packB, wB, E, NR);
    range_deg<<<NR, 256, 0, stream>>>(packB, wB, baseOut, dinv, offs, N, E);
    csr_build<<<NR, 256, 0, stream>>>(packB, wB, baseOut, dinv, offs, es, en, N);

    // weight prep
    tconv_kernel<<<(F * H + 255) / 256, 256, 0, stream>>>(W1, W1T, F, H);
    tconv_kernel<<<(H * H2 + 255) / 256, 256, 0, stream>>>(Wc, WcT, H, H2);
    fold_kernel<<<1, 256, 0, stream>>>(Wm, Wl, bm, wmp, wmq, bpq);

    // h0 = bf16(x @ W1 + b1)
    gemm1_mfma<<<nbM, 256, 0, stream>>>(x, W1T, b1, h0_bf, N);
    // agg1 = bf16(A @ h0)
    aggregate_bf16<<<nbW, 256, 0, stream>>>(h0_bf, offs, es, en, dinv, agg1_bf, N);
    // pe,qe = relu(agg1 @ Wc + bc) @ [wmp, wmq]
    gemm2_pq<<<nbM, 512, 0, stream>>>(agg1_bf, WcT, bc, wmp, wmq, pe, qe, N);
    // p,q scalar aggregation
    agg_scalar<<<nbN, 256, 0, stream>>>(pe, qe, offs, es, en, dinv, bpq, p, q, N);
    // out
    edge_out_kernel<<<nbE, 256, 0, stream>>>(src, dst, p, q, bl, out, E);
}